// Round 1
// baseline (1190.244 us; speedup 1.0000x reference)
//
#include <hip/hip_runtime.h>
#include <cstdint>

#define B_      32
#define N_      32768
#define C_      81
#define NCLS    80      // last class (background) skipped
#define TOPK    200
#define CONF_T  0.01f
#define IOU_T   0.45f
#define CAP     1024
#define NTH     256

// bucket = (bits(v) >> 13) - 129024 maps [0.5, 1.0) -> [0, 1024); monotone in v.
#define HBASE   129024
#define HBUCK   1024

__global__ __launch_bounds__(NTH) void nms_all(const float* __restrict__ conf,
                                               const float* __restrict__ loc,
                                               float* __restrict__ out) {
#pragma clang fp contract(off)
    const int bc  = blockIdx.x;          // b * 80 + c
    const int b   = bc / NCLS;
    const int c   = bc - b * NCLS;
    const int tid = threadIdx.x;

    __shared__ int    hist[HBUCK];
    __shared__ float  cand_val[CAP];
    __shared__ int    cand_idx[CAP];
    __shared__ int    cand_cnt;
    __shared__ int    cutoff_bucket;
    __shared__ float  top_val[TOPK];
    __shared__ int    top_idx[TOPK];
    __shared__ float4 box_s[TOPK];   // raw centroid cx,cy,w,h
    __shared__ float4 cor_s[TOPK];   // corners xmin,ymin,xmax,ymax
    __shared__ int    keep_s[TOPK];

    for (int k = tid; k < HBUCK; k += NTH) hist[k] = 0;
    if (tid == 0) cand_cnt = 0;
    __syncthreads();

    const float* col = conf + ((size_t)b * N_) * C_ + c;

    // ---- pass 1: histogram of conf values >= 0.5 (float-bit buckets) ----
    for (int n = tid; n < N_; n += NTH) {
        float v = col[(size_t)n * C_];
        if (v >= 0.5f) {
            int bkt = (int)(__float_as_uint(v) >> 13) - HBASE;
            bkt = min(bkt, HBUCK - 1);
            atomicAdd(&hist[bkt], 1);
        }
    }
    __syncthreads();

    // ---- exact suffix scan: smallest bucket with cumulative count >= TOPK ----
    if (tid == 0) {
        int acc = 0, cut = -1;
        for (int k = HBUCK - 1; k >= 0; --k) {
            acc += hist[k];
            if (acc >= TOPK) { cut = k; break; }
        }
        cutoff_bucket = cut;   // -1: fewer than 200 above 0.5 -> fallback
    }
    __syncthreads();

    const int   cut  = cutoff_bucket;
    const float vcut = (cut >= 0) ? __uint_as_float((uint32_t)(HBASE + cut) << 13)
                                  : CONF_T;

    // ---- pass 2: gather candidate superset of the top-200 ----
    for (int n = tid; n < N_; n += NTH) {
        float v = col[(size_t)n * C_];
        bool take = (cut >= 0) ? (v >= vcut) : (v > CONF_T);
        if (take) {
            int p = atomicAdd(&cand_cnt, 1);
            if (p < CAP) { cand_val[p] = v; cand_idx[p] = n; }
        }
    }
    for (int k = tid; k < TOPK; k += NTH) { top_idx[k] = -1; top_val[k] = -1.0f; }
    __syncthreads();

    int M = cand_cnt; if (M > CAP) M = CAP;

    // ---- exact rank selection: key = (value desc, index asc); keys unique ----
    for (int i = tid; i < M; i += NTH) {
        const uint32_t vb = __float_as_uint(cand_val[i]);
        const int      ii = cand_idx[i];
        int rank = 0;
        for (int j = 0; j < M; ++j) {
            uint32_t vj = __float_as_uint(cand_val[j]);
            rank += (vj > vb) || (vj == vb && cand_idx[j] < ii);
        }
        if (rank < TOPK) { top_val[rank] = cand_val[i]; top_idx[rank] = ii; }
    }
    __syncthreads();

    // ---- boxes + corners (FP-contract OFF to match numpy/XLA f32 exactly) ----
    if (tid < TOPK) {
        int idx = top_idx[tid];
        float4 bx = make_float4(-1.f, -1.f, -1.f, -1.f);
        float4 cr = make_float4(0.f, 0.f, 0.f, 0.f);
        int kp = 0;
        if (idx >= 0) {
            bx = *(const float4*)(loc + ((size_t)b * N_ + (size_t)idx) * 4);
            float hw = bx.z * 0.5f;
            float hh = bx.w * 0.5f;
            cr.x = bx.x - hw; cr.y = bx.y - hh;
            cr.z = bx.x + hw; cr.w = bx.y + hh;
            kp = 1;
        }
        box_s[tid] = bx; cor_s[tid] = cr; keep_s[tid] = kp;
    }
    __syncthreads();

    // ---- greedy serial NMS, reference semantics ----
    for (int i = 0; i < TOPK - 1; ++i) {
        if (keep_s[i]) {                       // block-uniform branch
            int j = tid;
            if (j > i && j < TOPK && keep_s[j]) {
                float4 a = cor_s[i], d = cor_s[j];
                float ltx = fmaxf(a.x, d.x), lty = fmaxf(a.y, d.y);
                float rbx = fminf(a.z, d.z), rby = fminf(a.w, d.w);
                float w  = fmaxf(rbx - ltx, 0.0f);
                float h  = fmaxf(rby - lty, 0.0f);
                float inter = w * h;
                float areaA = (a.z - a.x) * (a.w - a.y);
                float areaB = (d.z - d.x) * (d.w - d.y);
                float iou = inter / (areaA + areaB - inter);
                if (iou > IOU_T) keep_s[j] = 0;
            }
        }
        __syncthreads();
    }

    // ---- write output: boxes (B,80,200,6) then keep (B,80,200) ----
    if (tid < TOPK) {
        const size_t row = (size_t)bc * TOPK + tid;
        float* o = out + row * 6;
        float4 bx = box_s[tid];
        if (keep_s[tid]) {
            o[0] = (float)c;      o[1] = top_val[tid];
            o[2] = bx.x; o[3] = bx.y; o[4] = bx.z; o[5] = bx.w;
        } else {
            o[0] = -1.f; o[1] = -1.f; o[2] = -1.f;
            o[3] = -1.f; o[4] = -1.f; o[5] = -1.f;
        }
        out[(size_t)B_ * NCLS * TOPK * 6 + row] = keep_s[tid] ? 1.0f : 0.0f;
    }
}

extern "C" void kernel_launch(void* const* d_in, const int* in_sizes, int n_in,
                              void* d_out, int out_size, void* d_ws, size_t ws_size,
                              hipStream_t stream) {
    (void)in_sizes; (void)n_in; (void)d_ws; (void)ws_size; (void)out_size;
    const float* loc  = (const float*)d_in[0];
    const float* conf = (const float*)d_in[1];
    float* out = (float*)d_out;
    hipLaunchKernelGGL(nms_all, dim3(B_ * NCLS), dim3(NTH), 0, stream,
                       conf, loc, out);
}

// Round 2
// 979.974 us; speedup vs baseline: 1.2146x; 1.2146x over previous
//
#include <hip/hip_runtime.h>
#include <cstdint>

#define B_      32
#define N_      32768
#define C_      81
#define NCLS    80      // last class (background) skipped
#define TOPK    200
#define CONF_T  0.01f
#define IOU_T   0.45f
#define NTH     256
#define NBC     (B_ * NCLS)          // 2560 (b,c) tasks

// ---- fast-path pre-filter: THR = 1 - 2^-6 = 0.984375 ----
// P(v >= THR) = 1/64 -> count per (b,c) ~ Binom(32768, 1/64): mean 512, sd 22.6.
// [TOPK, CAP2] = [200,1024] is ~[-13.8sd, +22.6sd] -> fast path essentially always.
#define THR_F    0.984375f
#define THR_BITS 0x3F7C0000u         // bits(0.984375); [THR,1.0) spans 2^18 bit-codes
#define CAP2     1024

// slow-path histogram (round-1 style): buckets over [0.5,1.0) via float bits
#define HBASE   129024
#define HBUCK   1024

// ws layout (bytes)
#define OFF_CNT  0
#define OFF_VAL  16384
#define OFF_IDX  (16384 + (size_t)NBC * CAP2 * 4)
#define WS_NEED  (OFF_IDX + (size_t)NBC * CAP2 * 4)

__global__ void zero_cnt(int* __restrict__ cnt) {
    int i = blockIdx.x * blockDim.x + threadIdx.x;
    if (i < NBC) cnt[i] = 0;
}

// Coalesced single sweep of conf (B,N,C); compact (val,anchor) per (b,c).
__global__ __launch_bounds__(NTH) void filter_k(const float* __restrict__ conf,
                                                int* __restrict__ cnt,
                                                float* __restrict__ cval,
                                                int* __restrict__ cidx) {
    const uint32_t total4 = (uint32_t)((size_t)B_ * N_ * C_ / 4);  // 21,233,664
    const uint32_t stride = gridDim.x * blockDim.x;
    for (uint32_t q = blockIdx.x * blockDim.x + threadIdx.x; q < total4; q += stride) {
        float4 v4 = ((const float4*)conf)[q];
        if (v4.x < THR_F && v4.y < THR_F && v4.z < THR_F && v4.w < THR_F) continue;
        float vv[4] = {v4.x, v4.y, v4.z, v4.w};
        uint32_t base = q * 4u;
#pragma unroll
        for (int k = 0; k < 4; ++k) {
            if (vv[k] >= THR_F) {
                uint32_t i = base + (uint32_t)k;
                uint32_t c = i % C_;
                uint32_t t = i / C_;             // global anchor id
                if (c < NCLS) {
                    uint32_t n  = t & (N_ - 1);
                    uint32_t b  = t >> 15;
                    uint32_t bc = b * NCLS + c;
                    int p = atomicAdd(&cnt[bc], 1);
                    if (p < CAP2) {
                        cval[(size_t)bc * CAP2 + p] = vv[k];
                        cidx[(size_t)bc * CAP2 + p] = (int)n;
                    }
                }
            }
        }
    }
}

__global__ __launch_bounds__(NTH) void select_nms_k(const float* __restrict__ conf,
                                                    const float* __restrict__ loc,
                                                    const int* __restrict__ cnt,
                                                    const float* __restrict__ cval_g,
                                                    const int* __restrict__ cidx_g,
                                                    float* __restrict__ out,
                                                    int use_ws) {
#pragma clang fp contract(off)
    const int bc  = blockIdx.x;
    const int b   = bc / NCLS;
    const int c   = bc - b * NCLS;
    const int tid = threadIdx.x;

    __shared__ float  sval[CAP2];
    __shared__ int    sidx[CAP2];
    __shared__ int    hist[HBUCK];          // slow path uses 1024, fast uses 256
    __shared__ int    scnt;
    __shared__ int    cutoff;
    __shared__ float  top_val[TOPK];
    __shared__ int    top_idx[TOPK];
    __shared__ float4 box_s[TOPK];
    __shared__ float4 cor_s[TOPK];
    __shared__ unsigned long long sup[TOPK][4];
    __shared__ unsigned long long keepw[4];

    int M = use_ws ? cnt[bc] : 0;
    const bool fast = use_ws && (M >= TOPK) && (M <= CAP2);

    if (fast) {
        // ---------------- fast path: candidates already compacted ----------------
        const float* vsrc = cval_g + (size_t)bc * CAP2;
        const int*   isrc = cidx_g + (size_t)bc * CAP2;
        for (int i = tid; i < M; i += NTH) { sval[i] = vsrc[i]; sidx[i] = isrc[i]; }
        hist[tid] = 0;                       // NTH == 256 buckets
        __syncthreads();
        for (int i = tid; i < M; i += NTH) {
            uint32_t bkt = (__float_as_uint(sval[i]) - THR_BITS) >> 10;
            atomicAdd(&hist[bkt > 255u ? 255u : bkt], 1);
        }
        __syncthreads();
        if (tid == 0) {
            int acc = 0, cut = 0;
            for (int k = 255; k >= 0; --k) { acc += hist[k]; if (acc >= TOPK) { cut = k; break; } }
            cutoff = cut;
        }
        for (int k = tid; k < TOPK; k += NTH) { top_idx[k] = -1; top_val[k] = -1.0f; }
        __syncthreads();
        const uint32_t edge = THR_BITS + ((uint32_t)cutoff << 10);
        // exact rank among all M (ties: lower anchor index first == lax.top_k)
        for (int i = tid; i < M; i += NTH) {
            uint32_t vb = __float_as_uint(sval[i]);
            if (vb < edge) continue;         // ~200 survivors do the O(M) scan
            int ii = sidx[i];
            int rank = 0;
            for (int j = 0; j < M; ++j) {
                uint32_t vj = __float_as_uint(sval[j]);
                rank += (vj > vb) || (vj == vb && sidx[j] < ii);
            }
            if (rank < TOPK) { top_val[rank] = sval[i]; top_idx[rank] = ii; }
        }
        __syncthreads();
    } else {
        // ---------------- slow path: round-1 logic (any distribution) ----------------
        for (int k = tid; k < HBUCK; k += NTH) hist[k] = 0;
        if (tid == 0) scnt = 0;
        __syncthreads();
        const float* col = conf + ((size_t)b * N_) * C_ + c;
        for (int n = tid; n < N_; n += NTH) {
            float v = col[(size_t)n * C_];
            if (v >= 0.5f) {
                int bkt = (int)(__float_as_uint(v) >> 13) - HBASE;
                atomicAdd(&hist[min(bkt, HBUCK - 1)], 1);
            }
        }
        __syncthreads();
        if (tid == 0) {
            int acc = 0, cut = -1;
            for (int k = HBUCK - 1; k >= 0; --k) { acc += hist[k]; if (acc >= TOPK) { cut = k; break; } }
            cutoff = cut;
        }
        __syncthreads();
        const int   cutv = cutoff;
        const float vcut = (cutv >= 0) ? __uint_as_float((uint32_t)(HBASE + cutv) << 13) : CONF_T;
        for (int n = tid; n < N_; n += NTH) {
            float v = col[(size_t)n * C_];
            bool take = (cutv >= 0) ? (v >= vcut) : (v > CONF_T);
            if (take) {
                int p = atomicAdd(&scnt, 1);
                if (p < CAP2) { sval[p] = v; sidx[p] = n; }
            }
        }
        for (int k = tid; k < TOPK; k += NTH) { top_idx[k] = -1; top_val[k] = -1.0f; }
        __syncthreads();
        int MM = min(scnt, CAP2);
        for (int i = tid; i < MM; i += NTH) {
            uint32_t vb = __float_as_uint(sval[i]);
            int ii = sidx[i];
            int rank = 0;
            for (int j = 0; j < MM; ++j) {
                uint32_t vj = __float_as_uint(sval[j]);
                rank += (vj > vb) || (vj == vb && sidx[j] < ii);
            }
            if (rank < TOPK) { top_val[rank] = sval[i]; top_idx[rank] = ii; }
        }
        __syncthreads();
    }

    // ---------------- shared tail: boxes, corners, bitmask NMS, write ----------------
    if (tid < TOPK) {
        int idx = top_idx[tid];
        float4 bx = make_float4(-1.f, -1.f, -1.f, -1.f);
        float4 cr = make_float4(0.f, 0.f, 0.f, 0.f);
        if (idx >= 0) {
            bx = *(const float4*)(loc + ((size_t)b * N_ + (size_t)idx) * 4);
            float hw = bx.z * 0.5f;
            float hh = bx.w * 0.5f;
            cr.x = bx.x - hw; cr.y = bx.y - hh;
            cr.z = bx.x + hw; cr.w = bx.y + hh;
        }
        box_s[tid] = bx; cor_s[tid] = cr;
    }
    __syncthreads();

    // keep-init (valid = rank filled), one ballot per wave
    {
        bool v = (tid < TOPK) && (top_idx[tid] >= 0);
        unsigned long long m = __ballot(v);
        if ((tid & 63) == 0) keepw[tid >> 6] = m;
    }

    // suppression bitmask: wave w owns 64-column word w of every row
    {
        const int wave = tid >> 6, lane = tid & 63;
        const int j = (wave << 6) + lane;
        float4 d = make_float4(0.f, 0.f, 0.f, 0.f);
        const bool jv = (j < TOPK);
        if (jv) d = cor_s[j];
        const float areaB = (d.z - d.x) * (d.w - d.y);
        for (int i = 0; i < TOPK; ++i) {
            float4 a = cor_s[i];             // LDS broadcast
            bool s = false;
            if (jv && j > i) {
                float ltx = fmaxf(a.x, d.x), lty = fmaxf(a.y, d.y);
                float rbx = fminf(a.z, d.z), rby = fminf(a.w, d.w);
                float w  = fmaxf(rbx - ltx, 0.0f);
                float h  = fmaxf(rby - lty, 0.0f);
                float inter = w * h;
                float areaA = (a.z - a.x) * (a.w - a.y);
                float iou = inter / (areaA + areaB - inter);
                s = iou > IOU_T;
            }
            unsigned long long m = __ballot(s);
            if (lane == 0) sup[i][wave] = m;
        }
    }
    __syncthreads();

    // greedy scan: 200 iterations of 4x 64-bit ANDs on one thread
    if (tid == 0) {
        unsigned long long k0 = keepw[0], k1 = keepw[1], k2 = keepw[2], k3 = keepw[3];
        for (int i = 0; i < TOPK; ++i) {
            unsigned long long bit;
            switch (i >> 6) {
                case 0:  bit = (k0 >> (i      )) & 1ull; break;
                case 1:  bit = (k1 >> (i - 64 )) & 1ull; break;
                case 2:  bit = (k2 >> (i - 128)) & 1ull; break;
                default: bit = (k3 >> (i - 192)) & 1ull; break;
            }
            if (bit) {
                k0 &= ~sup[i][0]; k1 &= ~sup[i][1];
                k2 &= ~sup[i][2]; k3 &= ~sup[i][3];
            }
        }
        keepw[0] = k0; keepw[1] = k1; keepw[2] = k2; keepw[3] = k3;
    }
    __syncthreads();

    if (tid < TOPK) {
        const bool kp = (keepw[tid >> 6] >> (tid & 63)) & 1ull;
        const size_t row = (size_t)bc * TOPK + tid;
        float* o = out + row * 6;
        float4 bx = box_s[tid];
        if (kp) {
            o[0] = (float)c;   o[1] = top_val[tid];
            o[2] = bx.x; o[3] = bx.y; o[4] = bx.z; o[5] = bx.w;
        } else {
            o[0] = -1.f; o[1] = -1.f; o[2] = -1.f;
            o[3] = -1.f; o[4] = -1.f; o[5] = -1.f;
        }
        out[(size_t)NBC * TOPK * 6 + row] = kp ? 1.0f : 0.0f;
    }
}

extern "C" void kernel_launch(void* const* d_in, const int* in_sizes, int n_in,
                              void* d_out, int out_size, void* d_ws, size_t ws_size,
                              hipStream_t stream) {
    (void)in_sizes; (void)n_in; (void)out_size;
    const float* loc  = (const float*)d_in[0];
    const float* conf = (const float*)d_in[1];
    float* out = (float*)d_out;

    const bool use_ws = (d_ws != nullptr) && (ws_size >= WS_NEED);
    int*   cnt  = (int*)((char*)d_ws + OFF_CNT);
    float* cval = (float*)((char*)d_ws + OFF_VAL);
    int*   cidx = (int*)((char*)d_ws + OFF_IDX);

    if (use_ws) {
        hipLaunchKernelGGL(zero_cnt, dim3((NBC + NTH - 1) / NTH), dim3(NTH), 0, stream, cnt);
        hipLaunchKernelGGL(filter_k, dim3(2048), dim3(NTH), 0, stream, conf, cnt, cval, cidx);
    }
    hipLaunchKernelGGL(select_nms_k, dim3(NBC), dim3(NTH), 0, stream,
                       conf, loc, cnt, cval, cidx, out, use_ws ? 1 : 0);
}

// Round 3
// 644.815 us; speedup vs baseline: 1.8459x; 1.5198x over previous
//
#include <hip/hip_runtime.h>
#include <cstdint>

#define B_      32
#define N_      32768
#define C_      81
#define NCLS    80      // last class (background) skipped
#define TOPK    200
#define CONF_T  0.01f
#define IOU_T   0.45f
#define NTH     256
#define NBC     (B_ * NCLS)          // 2560 (b,c) tasks

// ---- fast-path pre-filter: THR = 1 - 2^-6 = 0.984375 ----
// P(v >= THR) = 1/64 -> per-(b,c) count ~ Binom(32768,1/64): mean 512, sd 22.6.
// [TOPK, CAP2] = [200,768] is [-13.8sd, +11.3sd] -> fast path essentially always.
#define THR_F    0.984375f
#define THR_BITS 0x3F7C0000u         // bits(0.984375); [THR,1.0) spans 2^18 codes
#define CAP2     768

// slow-path histogram buckets over [0.5,1.0) via float bits
#define HBASE   129024
#define HBUCK   1024

// ws layout (bytes)
#define OFF_CNT  0
#define OFF_VAL  16384
#define OFF_IDX  (16384 + (size_t)NBC * CAP2 * 4)
#define WS_NEED  (OFF_IDX + (size_t)NBC * CAP2 * 4)

#define UNROLL  8

__global__ void zero_cnt(int* __restrict__ cnt) {
    int i = blockIdx.x * blockDim.x + threadIdx.x;
    if (i < NBC) cnt[i] = 0;
}

__device__ __forceinline__ void emit_cand(uint32_t i, float v, int* cnt,
                                          float* cval, int* cidx) {
    uint32_t c = i % C_;
    uint32_t t = i / C_;                 // b*N + n
    if (c < NCLS) {
        uint32_t n  = t & (N_ - 1);
        uint32_t b  = t >> 15;
        uint32_t bc = b * NCLS + c;
        int p = atomicAdd(&cnt[bc], 1);
        if (p < CAP2) {
            cval[(size_t)bc * CAP2 + p] = v;
            cidx[(size_t)bc * CAP2 + p] = (int)n;
        }
    }
}

__device__ __forceinline__ void process4(float4 x, uint32_t q, int* cnt,
                                         float* cval, int* cidx) {
    if (x.x >= THR_F || x.y >= THR_F || x.z >= THR_F || x.w >= THR_F) {
        uint32_t base = q * 4u;
        if (x.x >= THR_F) emit_cand(base + 0u, x.x, cnt, cval, cidx);
        if (x.y >= THR_F) emit_cand(base + 1u, x.y, cnt, cval, cidx);
        if (x.z >= THR_F) emit_cand(base + 2u, x.z, cnt, cval, cidx);
        if (x.w >= THR_F) emit_cand(base + 3u, x.w, cnt, cval, cidx);
    }
}

// Coalesced sweep of conf with 8-deep register load batches (MLP).
__global__ __launch_bounds__(NTH) void filter_k(const float* __restrict__ conf,
                                                int* __restrict__ cnt,
                                                float* __restrict__ cval,
                                                int* __restrict__ cidx) {
    const uint32_t total4    = (uint32_t)((size_t)B_ * N_ * C_ / 4);  // 21,233,664
    const uint32_t chunk     = NTH * UNROLL;                           // 2048
    const uint32_t per_super = gridDim.x * chunk;
    const uint32_t nfull     = total4 / per_super;
    const float4*  c4        = (const float4*)conf;

    uint32_t base = blockIdx.x * chunk + threadIdx.x;
    for (uint32_t s = 0; s < nfull; ++s, base += per_super) {
        float4 v[UNROLL];
#pragma unroll
        for (int u = 0; u < UNROLL; ++u) v[u] = c4[base + u * NTH];
#pragma unroll
        for (int u = 0; u < UNROLL; ++u)
            process4(v[u], base + u * NTH, cnt, cval, cidx);
    }
    // tail
    for (uint32_t q = nfull * per_super + blockIdx.x * blockDim.x + threadIdx.x;
         q < total4; q += gridDim.x * blockDim.x) {
        process4(c4[q], q, cnt, cval, cidx);
    }
}

// ---- shared-memory layout (single buffer, byte offsets) ----
#define SM_SVAL   0                      // float[CAP2]            3072
#define SM_SIDX   3072                   // int[CAP2]              3072
#define SM_HIST   6144                   // int[1024] slow / int[256] fast
#define SM_SV2    10240                  // float[CAP2] fast; also ostage float[1200]
#define SM_SI2    13312                  // int[CAP2]
#define SM_TVAL   16384                  // float[TOPK]            800
#define SM_TIDX   17184                  // int[TOPK]              800
#define SM_BOX    17984                  // float4[TOPK]           3200
#define SM_COR    21184                  // float4[TOPK]           3200
#define SM_SUP    24384                  // u64[TOPK][4]           6400
#define SM_KEEPW  30784                  // u64[4]                 32
#define SM_CTRL   30816                  // int[4]: scnt, cutoff, nsurv
#define SM_TOTAL  30848

__global__ __launch_bounds__(NTH) void select_nms_k(const float* __restrict__ conf,
                                                    const float* __restrict__ loc,
                                                    const int* __restrict__ cnt,
                                                    const float* __restrict__ cval_g,
                                                    const int* __restrict__ cidx_g,
                                                    float* __restrict__ out,
                                                    int use_ws) {
#pragma clang fp contract(off)
    const int bc  = blockIdx.x;
    const int b   = bc / NCLS;
    const int c   = bc - b * NCLS;
    const int tid = threadIdx.x;

    __shared__ __align__(16) char smem[SM_TOTAL];
    float*  sval   = (float*)(smem + SM_SVAL);
    int*    sidx   = (int*)(smem + SM_SIDX);
    int*    hist   = (int*)(smem + SM_HIST);
    float*  sv2    = (float*)(smem + SM_SV2);
    int*    si2    = (int*)(smem + SM_SI2);
    float*  ostage = (float*)(smem + SM_SV2);           // reuse (dead by write stage)
    float*  top_val = (float*)(smem + SM_TVAL);
    int*    top_idx = (int*)(smem + SM_TIDX);
    float4* box_s  = (float4*)(smem + SM_BOX);
    float4* cor_s  = (float4*)(smem + SM_COR);
    unsigned long long* sup   = (unsigned long long*)(smem + SM_SUP);   // [i*4+w]
    unsigned long long* keepw = (unsigned long long*)(smem + SM_KEEPW);
    int* ctrl = (int*)(smem + SM_CTRL);   // [0]=scnt [1]=cutoff [2]=nsurv

    int M = use_ws ? cnt[bc] : 0;
    const bool fast = use_ws && (M >= TOPK) && (M <= CAP2);

    if (fast) {
        // ------------- fast path: candidates pre-compacted by filter_k -------------
        const float* vsrc = cval_g + (size_t)bc * CAP2;
        const int*   isrc = cidx_g + (size_t)bc * CAP2;
        for (int i = tid; i < M; i += NTH) { sval[i] = vsrc[i]; sidx[i] = isrc[i]; }
        hist[tid] = 0;                                   // 256 buckets
        if (tid == 0) ctrl[2] = 0;
        if (tid < TOPK) { top_idx[tid] = -1; top_val[tid] = -1.0f; }
        __syncthreads();

        for (int i = tid; i < M; i += NTH) {
            uint32_t bkt = (__float_as_uint(sval[i]) - THR_BITS) >> 10;
            atomicAdd(&hist[bkt > 255u ? 255u : bkt], 1);
        }
        __syncthreads();

        if (tid == 0) {                                  // int4-pipelined suffix scan
            int acc = 0, cut = 0;
            for (int k4 = 63; k4 >= 0; --k4) {
                int4 h = ((int4*)hist)[k4];
                int t3 = acc + h.w, t2 = t3 + h.z, t1 = t2 + h.y, t0 = t1 + h.x;
                if (t0 >= TOPK) {
                    cut = (t3 >= TOPK) ? k4 * 4 + 3 : (t2 >= TOPK) ? k4 * 4 + 2
                        : (t1 >= TOPK) ? k4 * 4 + 1 : k4 * 4;
                    break;
                }
                acc = t0;
            }
            ctrl[1] = cut;
        }
        __syncthreads();

        const uint32_t edge = THR_BITS + ((uint32_t)ctrl[1] << 10);
        for (int i = tid; i < M; i += NTH) {             // survivor compaction
            if (__float_as_uint(sval[i]) >= edge) {
                int p = atomicAdd(&ctrl[2], 1);
                sv2[p] = sval[i]; si2[p] = sidx[i];
            }
        }
        __syncthreads();

        const int S = ctrl[2];                           // ~200-230
        for (int i = tid; i < S; i += NTH) {             // exact rank among survivors
            float    v  = sv2[i];
            uint32_t vb = __float_as_uint(v);
            int      ii = si2[i];
            int rank = 0;
#pragma unroll 4
            for (int j = 0; j < S; ++j) {
                uint32_t vj = __float_as_uint(sv2[j]);
                rank += (vj > vb) || (vj == vb && si2[j] < ii);
            }
            if (rank < TOPK) { top_val[rank] = v; top_idx[rank] = ii; }
        }
        __syncthreads();
    } else {
        // ------------- slow path: strided re-read of conf (robust fallback) -------------
        for (int k = tid; k < HBUCK; k += NTH) hist[k] = 0;
        if (tid == 0) ctrl[0] = 0;
        if (tid < TOPK) { top_idx[tid] = -1; top_val[tid] = -1.0f; }
        __syncthreads();
        const float* col = conf + ((size_t)b * N_) * C_ + c;
        for (int n = tid; n < N_; n += NTH) {
            float v = col[(size_t)n * C_];
            if (v >= 0.5f) {
                int bkt = (int)(__float_as_uint(v) >> 13) - HBASE;
                atomicAdd(&hist[min(bkt, HBUCK - 1)], 1);
            }
        }
        __syncthreads();
        if (tid == 0) {
            int acc = 0, cut = -1;
            for (int k = HBUCK - 1; k >= 0; --k) {
                acc += hist[k];
                if (acc >= TOPK) { cut = k; break; }
            }
            ctrl[1] = cut;
        }
        __syncthreads();
        const int   cutv = ctrl[1];
        const float vcut = (cutv >= 0) ? __uint_as_float((uint32_t)(HBASE + cutv) << 13)
                                       : CONF_T;
        for (int n = tid; n < N_; n += NTH) {
            float v = col[(size_t)n * C_];
            bool take = (cutv >= 0) ? (v >= vcut) : (v > CONF_T);
            if (take) {
                int p = atomicAdd(&ctrl[0], 1);
                if (p < CAP2) { sval[p] = v; sidx[p] = n; }
            }
        }
        __syncthreads();
        int MM = min(ctrl[0], CAP2);
        for (int i = tid; i < MM; i += NTH) {
            uint32_t vb = __float_as_uint(sval[i]);
            int ii = sidx[i];
            int rank = 0;
            for (int j = 0; j < MM; ++j) {
                uint32_t vj = __float_as_uint(sval[j]);
                rank += (vj > vb) || (vj == vb && sidx[j] < ii);
            }
            if (rank < TOPK) { top_val[rank] = sval[i]; top_idx[rank] = ii; }
        }
        __syncthreads();
    }

    // ------------- common tail: boxes, corners, bitmask NMS, write -------------
    if (tid < TOPK) {
        int idx = top_idx[tid];
        float4 bx = make_float4(-1.f, -1.f, -1.f, -1.f);
        float4 cr = make_float4(0.f, 0.f, 0.f, 0.f);
        if (idx >= 0) {
            bx = *(const float4*)(loc + ((size_t)b * N_ + (size_t)idx) * 4);
            float hw = bx.z * 0.5f;
            float hh = bx.w * 0.5f;
            cr.x = bx.x - hw; cr.y = bx.y - hh;
            cr.z = bx.x + hw; cr.w = bx.y + hh;
        }
        box_s[tid] = bx; cor_s[tid] = cr;
    }
    __syncthreads();

    {   // keep-init: one ballot per wave
        bool v = (tid < TOPK) && (top_idx[tid] >= 0);
        unsigned long long m = __ballot(v);
        if ((tid & 63) == 0) keepw[tid >> 6] = m;
    }

    {   // suppression bitmask: wave w owns column word w of every row
        const int wave = tid >> 6, lane = tid & 63;
        const int j = (wave << 6) + lane;
        float4 d = make_float4(0.f, 0.f, 0.f, 0.f);
        const bool jv = (j < TOPK);
        if (jv) d = cor_s[j];
        const float areaB = (d.z - d.x) * (d.w - d.y);
#pragma unroll 2
        for (int i = 0; i < TOPK; ++i) {
            float4 a = cor_s[i];
            bool s = false;
            if (jv && j > i) {
                float ltx = fmaxf(a.x, d.x), lty = fmaxf(a.y, d.y);
                float rbx = fminf(a.z, d.z), rby = fminf(a.w, d.w);
                float w  = fmaxf(rbx - ltx, 0.0f);
                float h  = fmaxf(rby - lty, 0.0f);
                float inter = w * h;
                float areaA = (a.z - a.x) * (a.w - a.y);
                float iou = inter / (areaA + areaB - inter);
                s = iou > IOU_T;
            }
            unsigned long long m = __ballot(s);
            if (lane == 0) sup[i * 4 + wave] = m;
        }
    }
    __syncthreads();

    // greedy scan in wave 0 registers: lane l holds rows l, 64+l, 128+l, 192+l
    if (tid < 64) {
        unsigned long long r0[4], r1[4], r2[4], r3[4];
#pragma unroll
        for (int w = 0; w < 4; ++w) {
            r0[w] = sup[(0 * 64 + tid) * 4 + w];
            r1[w] = sup[(1 * 64 + tid) * 4 + w];
            r2[w] = sup[(2 * 64 + tid) * 4 + w];
            r3[w] = (192 + tid < TOPK) ? sup[(192 + tid) * 4 + w] : 0ull;
        }
        unsigned long long k0 = keepw[0], k1 = keepw[1], k2 = keepw[2], k3 = keepw[3];
#define GREEDY_BLK(KW, RR)                                            \
        for (int ii = 0; ii < 64; ++ii) {                             \
            if ((KW >> ii) & 1ull) {                                  \
                k0 &= ~__shfl(RR[0], ii);                             \
                k1 &= ~__shfl(RR[1], ii);                             \
                k2 &= ~__shfl(RR[2], ii);                             \
                k3 &= ~__shfl(RR[3], ii);                             \
            }                                                         \
        }
        GREEDY_BLK(k0, r0)
        GREEDY_BLK(k1, r1)
        GREEDY_BLK(k2, r2)
        GREEDY_BLK(k3, r3)
#undef GREEDY_BLK
        if (tid == 0) { keepw[0] = k0; keepw[1] = k1; keepw[2] = k2; keepw[3] = k3; }
    }
    __syncthreads();

    // stage 200x6 floats in LDS, flush as 300 coalesced float4
    if (tid < TOPK) {
        const bool kp = (keepw[tid >> 6] >> (tid & 63)) & 1ull;
        float4 bx = box_s[tid];
        float* o = ostage + tid * 6;
        if (kp) {
            o[0] = (float)c;   o[1] = top_val[tid];
            o[2] = bx.x; o[3] = bx.y; o[4] = bx.z; o[5] = bx.w;
        } else {
            o[0] = -1.f; o[1] = -1.f; o[2] = -1.f;
            o[3] = -1.f; o[4] = -1.f; o[5] = -1.f;
        }
        out[(size_t)NBC * TOPK * 6 + (size_t)bc * TOPK + tid] = kp ? 1.0f : 0.0f;
    }
    __syncthreads();
    {
        float4* dst = (float4*)(out + (size_t)bc * TOPK * 6);
        const float4* src = (const float4*)ostage;
        for (int k = tid; k < TOPK * 6 / 4; k += NTH) dst[k] = src[k];
    }
}

extern "C" void kernel_launch(void* const* d_in, const int* in_sizes, int n_in,
                              void* d_out, int out_size, void* d_ws, size_t ws_size,
                              hipStream_t stream) {
    (void)in_sizes; (void)n_in; (void)out_size;
    const float* loc  = (const float*)d_in[0];
    const float* conf = (const float*)d_in[1];
    float* out = (float*)d_out;

    const bool use_ws = (d_ws != nullptr) && (ws_size >= WS_NEED);
    int*   cnt  = (int*)((char*)d_ws + OFF_CNT);
    float* cval = (float*)((char*)d_ws + OFF_VAL);
    int*   cidx = (int*)((char*)d_ws + OFF_IDX);

    if (use_ws) {
        hipLaunchKernelGGL(zero_cnt, dim3((NBC + NTH - 1) / NTH), dim3(NTH), 0, stream, cnt);
        hipLaunchKernelGGL(filter_k, dim3(2048), dim3(NTH), 0, stream, conf, cnt, cval, cidx);
    }
    hipLaunchKernelGGL(select_nms_k, dim3(NBC), dim3(NTH), 0, stream,
                       conf, loc, cnt, cval, cidx, out, use_ws ? 1 : 0);
}

// Round 4
// 265.514 us; speedup vs baseline: 4.4828x; 2.4286x over previous
//
#include <hip/hip_runtime.h>
#include <cstdint>

#define B_      32
#define N_      32768
#define C_      81
#define NCLS    80      // last class (background) skipped
#define TOPK    200
#define CONF_T  0.01f
#define IOU_T   0.45f
#define NTH     256
#define NBC     (B_ * NCLS)          // 2560 (b,c) tasks

// ---- fast-path pre-filter: THR = 1 - 2^-6 = 0.984375 ----
// P(v >= THR) = 1/64 -> per-(b,c) count ~ Binom(32768,1/64): mean 512, sd 22.6.
// [TOPK, CAP2] = [200,768] is [-13.8sd, +11.3sd] -> fast path essentially always.
#define THR_F    0.984375f
#define THR_BITS 0x3F7C0000u         // bits(0.984375); [THR,1.0) spans 2^18 codes
#define CAP2     768

// filter blocking: one block per (b, 512-anchor slab)
#define ANCH_PB  512
#define NCHUNK   (N_ / ANCH_PB)      // 64
#define SLAB_F4  (ANCH_PB * C_ / 4)  // 10368 float4 per block
#define CAPB     1024                // LDS staging (mean 648, sd 25.3 -> +14.9sd)

// slow-path histogram buckets over [0.5,1.0) via float bits
#define HBASE   129024
#define HBUCK   1024

// ws layout (bytes): cnt[NBC] then cand[NBC][CAP2] as uint2(val_bits, anchor)
#define OFF_CNT  0
#define OFF_CAND 16384
#define WS_NEED  (OFF_CAND + (size_t)NBC * CAP2 * 8)

__global__ void zero_cnt(int* __restrict__ cnt) {
    int i = blockIdx.x * blockDim.x + threadIdx.x;
    if (i < NBC) cnt[i] = 0;
}

// One block per (b, 512-anchor slab): coalesced contiguous read, LDS-staged
// candidates, one global atomic per class per block.
__global__ __launch_bounds__(NTH) void filter_k(const float* __restrict__ conf,
                                                int* __restrict__ cnt,
                                                uint2* __restrict__ cand) {
    const int tid   = threadIdx.x;
    const int blk   = blockIdx.x;
    const int b     = blk >> 6;           // NCHUNK == 64
    const int chunk = blk & (NCHUNK - 1);
    const uint32_t n0 = (uint32_t)chunk * ANCH_PB;
    const float4* slab = (const float4*)(conf + ((size_t)b * N_ + n0) * C_);

    __shared__ uint2 stage[CAPB];
    __shared__ int   lhist[NCLS];
    __shared__ int   lpos[NCLS];
    __shared__ int   gbase[NCLS];
    __shared__ int   ltot;

    for (int k = tid; k < NCLS; k += NTH) { lhist[k] = 0; lpos[k] = 0; }
    if (tid == 0) ltot = 0;
    __syncthreads();

    auto emit = [&](uint32_t e, float v) {
        uint32_t c = e % (uint32_t)C_;     // magic-mul div by 81
        if (c < NCLS) {
            uint32_t nl = e / (uint32_t)C_;
            int q = atomicAdd(&ltot, 1);
            atomicAdd(&lhist[c], 1);
            if (q < CAPB)
                stage[q] = make_uint2(__float_as_uint(v), (c << 16) | nl);
        }
    };
    auto proc4 = [&](float4 x, uint32_t q) {
        if (x.x >= THR_F || x.y >= THR_F || x.z >= THR_F || x.w >= THR_F) {
            uint32_t e = q * 4u;
            if (x.x >= THR_F) emit(e + 0u, x.x);
            if (x.y >= THR_F) emit(e + 1u, x.y);
            if (x.z >= THR_F) emit(e + 2u, x.z);
            if (x.w >= THR_F) emit(e + 3u, x.w);
        }
    };

    // 10368 float4 = 5 supersteps of 8x256 + tail of 128
    uint32_t qb = (uint32_t)tid;
#pragma unroll 1
    for (int s = 0; s < 5; ++s, qb += 8 * NTH) {
        float4 v[8];
#pragma unroll
        for (int u = 0; u < 8; ++u) v[u] = slab[qb + u * NTH];
#pragma unroll
        for (int u = 0; u < 8; ++u) proc4(v[u], qb + u * NTH);
    }
    if (tid < SLAB_F4 - 5 * 8 * NTH) {     // tail: 128 float4
        uint32_t q = 5u * 8u * NTH + (uint32_t)tid;
        proc4(slab[q], q);
    }
    __syncthreads();

    const int tot = ltot;
    if (tot > CAPB) {                      // statistically never: force slow path
        for (int k = tid; k < NCLS; k += NTH)
            atomicAdd(&cnt[b * NCLS + k], CAP2 + 1);
        return;
    }
    if (tid < NCLS)
        gbase[tid] = atomicAdd(&cnt[b * NCLS + tid], lhist[tid]);
    __syncthreads();

    for (int q = tid; q < tot; q += NTH) {
        uint2 s = stage[q];
        uint32_t c  = s.y >> 16;
        uint32_t nl = s.y & 0xFFFFu;
        int pos = atomicAdd(&lpos[c], 1);
        int dst = gbase[c] + pos;
        if (dst < CAP2)
            cand[(size_t)(b * NCLS + c) * CAP2 + dst] = make_uint2(s.x, n0 + nl);
    }
}

// ---- shared-memory layout for select (single buffer, byte offsets) ----
#define SM_SVAL   0                      // float[CAP2]            3072
#define SM_SIDX   3072                   // int[CAP2]              3072
#define SM_HIST   6144                   // int[1024] slow / int[256] fast
#define SM_SV2    10240                  // float[CAP2] fast; also ostage float[1200]
#define SM_SI2    13312                  // int[CAP2]
#define SM_TVAL   16384                  // float[TOPK]            800
#define SM_TIDX   17184                  // int[TOPK]              800
#define SM_BOX    17984                  // float4[TOPK]           3200
#define SM_COR    21184                  // float4[TOPK]           3200
#define SM_SUP    24384                  // u64[TOPK][4]           6400
#define SM_KEEPW  30784                  // u64[4]                 32
#define SM_CTRL   30816                  // int[4]: scnt, cutoff, nsurv
#define SM_TOTAL  30848

__global__ __launch_bounds__(NTH) void select_nms_k(const float* __restrict__ conf,
                                                    const float* __restrict__ loc,
                                                    const int* __restrict__ cnt,
                                                    const uint2* __restrict__ cand,
                                                    float* __restrict__ out,
                                                    int use_ws) {
#pragma clang fp contract(off)
    const int bc  = blockIdx.x;
    const int b   = bc / NCLS;
    const int c   = bc - b * NCLS;
    const int tid = threadIdx.x;

    __shared__ __align__(16) char smem[SM_TOTAL];
    float*  sval   = (float*)(smem + SM_SVAL);
    int*    sidx   = (int*)(smem + SM_SIDX);
    int*    hist   = (int*)(smem + SM_HIST);
    float*  sv2    = (float*)(smem + SM_SV2);
    int*    si2    = (int*)(smem + SM_SI2);
    float*  ostage = (float*)(smem + SM_SV2);           // reuse (dead by write stage)
    float*  top_val = (float*)(smem + SM_TVAL);
    int*    top_idx = (int*)(smem + SM_TIDX);
    float4* box_s  = (float4*)(smem + SM_BOX);
    float4* cor_s  = (float4*)(smem + SM_COR);
    unsigned long long* sup   = (unsigned long long*)(smem + SM_SUP);   // [i*4+w]
    unsigned long long* keepw = (unsigned long long*)(smem + SM_KEEPW);
    int* ctrl = (int*)(smem + SM_CTRL);   // [0]=scnt [1]=cutoff [2]=nsurv

    int M = use_ws ? cnt[bc] : 0;
    const bool fast = use_ws && (M >= TOPK) && (M <= CAP2);

    if (fast) {
        // ------------- fast path: candidates pre-compacted by filter_k -------------
        const uint2* src = cand + (size_t)bc * CAP2;
        for (int i = tid; i < M; i += NTH) {
            uint2 s = src[i];
            sval[i] = __uint_as_float(s.x);
            sidx[i] = (int)s.y;
        }
        hist[tid] = 0;                                   // 256 buckets
        if (tid == 0) ctrl[2] = 0;
        if (tid < TOPK) { top_idx[tid] = -1; top_val[tid] = -1.0f; }
        __syncthreads();

        for (int i = tid; i < M; i += NTH) {
            uint32_t bkt = (__float_as_uint(sval[i]) - THR_BITS) >> 10;
            atomicAdd(&hist[bkt > 255u ? 255u : bkt], 1);
        }
        __syncthreads();

        if (tid == 0) {                                  // int4-pipelined suffix scan
            int acc = 0, cut = 0;
            for (int k4 = 63; k4 >= 0; --k4) {
                int4 h = ((int4*)hist)[k4];
                int t3 = acc + h.w, t2 = t3 + h.z, t1 = t2 + h.y, t0 = t1 + h.x;
                if (t0 >= TOPK) {
                    cut = (t3 >= TOPK) ? k4 * 4 + 3 : (t2 >= TOPK) ? k4 * 4 + 2
                        : (t1 >= TOPK) ? k4 * 4 + 1 : k4 * 4;
                    break;
                }
                acc = t0;
            }
            ctrl[1] = cut;
        }
        __syncthreads();

        const uint32_t edge = THR_BITS + ((uint32_t)ctrl[1] << 10);
        for (int i = tid; i < M; i += NTH) {             // survivor compaction
            if (__float_as_uint(sval[i]) >= edge) {
                int p = atomicAdd(&ctrl[2], 1);
                sv2[p] = sval[i]; si2[p] = sidx[i];
            }
        }
        __syncthreads();

        const int S = ctrl[2];                           // ~200-230
        for (int i = tid; i < S; i += NTH) {             // exact rank among survivors
            float    v  = sv2[i];
            uint32_t vb = __float_as_uint(v);
            int      ii = si2[i];
            int rank = 0;
#pragma unroll 4
            for (int j = 0; j < S; ++j) {
                uint32_t vj = __float_as_uint(sv2[j]);
                rank += (vj > vb) || (vj == vb && si2[j] < ii);
            }
            if (rank < TOPK) { top_val[rank] = v; top_idx[rank] = ii; }
        }
        __syncthreads();
    } else {
        // ------------- slow path: strided re-read of conf (robust fallback) -------------
        for (int k = tid; k < HBUCK; k += NTH) hist[k] = 0;
        if (tid == 0) ctrl[0] = 0;
        if (tid < TOPK) { top_idx[tid] = -1; top_val[tid] = -1.0f; }
        __syncthreads();
        const float* col = conf + ((size_t)b * N_) * C_ + c;
        for (int n = tid; n < N_; n += NTH) {
            float v = col[(size_t)n * C_];
            if (v >= 0.5f) {
                int bkt = (int)(__float_as_uint(v) >> 13) - HBASE;
                atomicAdd(&hist[min(bkt, HBUCK - 1)], 1);
            }
        }
        __syncthreads();
        if (tid == 0) {
            int acc = 0, cut = -1;
            for (int k = HBUCK - 1; k >= 0; --k) {
                acc += hist[k];
                if (acc >= TOPK) { cut = k; break; }
            }
            ctrl[1] = cut;
        }
        __syncthreads();
        const int   cutv = ctrl[1];
        const float vcut = (cutv >= 0) ? __uint_as_float((uint32_t)(HBASE + cutv) << 13)
                                       : CONF_T;
        for (int n = tid; n < N_; n += NTH) {
            float v = col[(size_t)n * C_];
            bool take = (cutv >= 0) ? (v >= vcut) : (v > CONF_T);
            if (take) {
                int p = atomicAdd(&ctrl[0], 1);
                if (p < CAP2) { sval[p] = v; sidx[p] = n; }
            }
        }
        __syncthreads();
        int MM = min(ctrl[0], CAP2);
        for (int i = tid; i < MM; i += NTH) {
            uint32_t vb = __float_as_uint(sval[i]);
            int ii = sidx[i];
            int rank = 0;
            for (int j = 0; j < MM; ++j) {
                uint32_t vj = __float_as_uint(sval[j]);
                rank += (vj > vb) || (vj == vb && sidx[j] < ii);
            }
            if (rank < TOPK) { top_val[rank] = sval[i]; top_idx[rank] = ii; }
        }
        __syncthreads();
    }

    // ------------- common tail: boxes, corners, bitmask NMS, write -------------
    if (tid < TOPK) {
        int idx = top_idx[tid];
        float4 bx = make_float4(-1.f, -1.f, -1.f, -1.f);
        float4 cr = make_float4(0.f, 0.f, 0.f, 0.f);
        if (idx >= 0) {
            bx = *(const float4*)(loc + ((size_t)b * N_ + (size_t)idx) * 4);
            float hw = bx.z * 0.5f;
            float hh = bx.w * 0.5f;
            cr.x = bx.x - hw; cr.y = bx.y - hh;
            cr.z = bx.x + hw; cr.w = bx.y + hh;
        }
        box_s[tid] = bx; cor_s[tid] = cr;
    }
    __syncthreads();

    {   // keep-init: one ballot per wave
        bool v = (tid < TOPK) && (top_idx[tid] >= 0);
        unsigned long long m = __ballot(v);
        if ((tid & 63) == 0) keepw[tid >> 6] = m;
    }

    {   // suppression bitmask: wave w owns column word w of every row
        const int wave = tid >> 6, lane = tid & 63;
        const int j = (wave << 6) + lane;
        float4 d = make_float4(0.f, 0.f, 0.f, 0.f);
        const bool jv = (j < TOPK);
        if (jv) d = cor_s[j];
        const float areaB = (d.z - d.x) * (d.w - d.y);
#pragma unroll 2
        for (int i = 0; i < TOPK; ++i) {
            float4 a = cor_s[i];
            bool s = false;
            if (jv && j > i) {
                float ltx = fmaxf(a.x, d.x), lty = fmaxf(a.y, d.y);
                float rbx = fminf(a.z, d.z), rby = fminf(a.w, d.w);
                float w  = fmaxf(rbx - ltx, 0.0f);
                float h  = fmaxf(rby - lty, 0.0f);
                float inter = w * h;
                float areaA = (a.z - a.x) * (a.w - a.y);
                float iou = inter / (areaA + areaB - inter);
                s = iou > IOU_T;
            }
            unsigned long long m = __ballot(s);
            if (lane == 0) sup[i * 4 + wave] = m;
        }
    }
    __syncthreads();

    // greedy scan in wave 0 registers: lane l holds rows l, 64+l, 128+l, 192+l
    if (tid < 64) {
        unsigned long long r0[4], r1[4], r2[4], r3[4];
#pragma unroll
        for (int w = 0; w < 4; ++w) {
            r0[w] = sup[(0 * 64 + tid) * 4 + w];
            r1[w] = sup[(1 * 64 + tid) * 4 + w];
            r2[w] = sup[(2 * 64 + tid) * 4 + w];
            r3[w] = (192 + tid < TOPK) ? sup[(192 + tid) * 4 + w] : 0ull;
        }
        unsigned long long k0 = keepw[0], k1 = keepw[1], k2 = keepw[2], k3 = keepw[3];
#define GREEDY_BLK(KW, RR)                                            \
        for (int ii = 0; ii < 64; ++ii) {                             \
            if ((KW >> ii) & 1ull) {                                  \
                k0 &= ~__shfl(RR[0], ii);                             \
                k1 &= ~__shfl(RR[1], ii);                             \
                k2 &= ~__shfl(RR[2], ii);                             \
                k3 &= ~__shfl(RR[3], ii);                             \
            }                                                         \
        }
        GREEDY_BLK(k0, r0)
        GREEDY_BLK(k1, r1)
        GREEDY_BLK(k2, r2)
        GREEDY_BLK(k3, r3)
#undef GREEDY_BLK
        if (tid == 0) { keepw[0] = k0; keepw[1] = k1; keepw[2] = k2; keepw[3] = k3; }
    }
    __syncthreads();

    // stage 200x6 floats in LDS, flush as 300 coalesced float4
    if (tid < TOPK) {
        const bool kp = (keepw[tid >> 6] >> (tid & 63)) & 1ull;
        float4 bx = box_s[tid];
        float* o = ostage + tid * 6;
        if (kp) {
            o[0] = (float)c;   o[1] = top_val[tid];
            o[2] = bx.x; o[3] = bx.y; o[4] = bx.z; o[5] = bx.w;
        } else {
            o[0] = -1.f; o[1] = -1.f; o[2] = -1.f;
            o[3] = -1.f; o[4] = -1.f; o[5] = -1.f;
        }
        out[(size_t)NBC * TOPK * 6 + (size_t)bc * TOPK + tid] = kp ? 1.0f : 0.0f;
    }
    __syncthreads();
    {
        float4* dst = (float4*)(out + (size_t)bc * TOPK * 6);
        const float4* src = (const float4*)ostage;
        for (int k = tid; k < TOPK * 6 / 4; k += NTH) dst[k] = src[k];
    }
}

extern "C" void kernel_launch(void* const* d_in, const int* in_sizes, int n_in,
                              void* d_out, int out_size, void* d_ws, size_t ws_size,
                              hipStream_t stream) {
    (void)in_sizes; (void)n_in; (void)out_size;
    const float* loc  = (const float*)d_in[0];
    const float* conf = (const float*)d_in[1];
    float* out = (float*)d_out;

    const bool use_ws = (d_ws != nullptr) && (ws_size >= WS_NEED);
    int*   cnt  = (int*)((char*)d_ws + OFF_CNT);
    uint2* cand = (uint2*)((char*)d_ws + OFF_CAND);

    if (use_ws) {
        hipLaunchKernelGGL(zero_cnt, dim3((NBC + NTH - 1) / NTH), dim3(NTH), 0, stream, cnt);
        hipLaunchKernelGGL(filter_k, dim3(B_ * NCHUNK), dim3(NTH), 0, stream,
                           conf, cnt, cand);
    }
    hipLaunchKernelGGL(select_nms_k, dim3(NBC), dim3(NTH), 0, stream,
                       conf, loc, cnt, cand, out, use_ws ? 1 : 0);
}

// Round 5
// 238.887 us; speedup vs baseline: 4.9825x; 1.1115x over previous
//
#include <hip/hip_runtime.h>
#include <cstdint>

#define B_      32
#define N_      32768
#define C_      81
#define NCLS    80      // last class (background) skipped
#define TOPK    200
#define CONF_T  0.01f
#define IOU_T   0.45f
#define NTH     256
#define NBC     (B_ * NCLS)          // 2560 (b,c) tasks

// ---- fast-path pre-filter: THR = 1 - 2^-6 = 0.984375 ----
// P(v >= THR) = 1/64 -> per-(b,c) count ~ Binom(32768,1/64): mean 512, sd 22.6.
// [TOPK, CAP2] = [200,768] is [-13.8sd, +11.3sd] -> fast path essentially always.
#define THR_F    0.984375f
#define THR_BITS 0x3F7C0000u         // bits(0.984375); [THR,1.0) spans 2^18 codes
#define CAP2     768

// filter blocking: one block per (b, 512-anchor slab)
#define ANCH_PB  512
#define NCHUNK   (N_ / ANCH_PB)      // 64
#define SLAB_F4  (ANCH_PB * C_ / 4)  // 10368 float4 per block
#define CAPB     1024                // LDS staging (mean 648, sd 25.3 -> +14.9sd)

// slow-path histogram buckets over [0.5,1.0) via float bits
#define HBASE   129024
#define HBUCK   1024

// ws layout (bytes): cnt[NBC] then cand[NBC][CAP2] as uint2(val_bits, anchor)
#define OFF_CNT  0
#define OFF_CAND 16384
#define WS_NEED  (OFF_CAND + (size_t)NBC * CAP2 * 8)

__global__ void zero_cnt(int* __restrict__ cnt) {
    int i = blockIdx.x * blockDim.x + threadIdx.x;
    if (i < NBC) cnt[i] = 0;
}

// One block per (b, 512-anchor slab): coalesced contiguous read, LDS-staged
// candidates, one global atomic per class per block.  (At HBM roofline - frozen.)
__global__ __launch_bounds__(NTH) void filter_k(const float* __restrict__ conf,
                                                int* __restrict__ cnt,
                                                uint2* __restrict__ cand) {
    const int tid   = threadIdx.x;
    const int blk   = blockIdx.x;
    const int b     = blk >> 6;           // NCHUNK == 64
    const int chunk = blk & (NCHUNK - 1);
    const uint32_t n0 = (uint32_t)chunk * ANCH_PB;
    const float4* slab = (const float4*)(conf + ((size_t)b * N_ + n0) * C_);

    __shared__ uint2 stage[CAPB];
    __shared__ int   lhist[NCLS];
    __shared__ int   lpos[NCLS];
    __shared__ int   gbase[NCLS];
    __shared__ int   ltot;

    for (int k = tid; k < NCLS; k += NTH) { lhist[k] = 0; lpos[k] = 0; }
    if (tid == 0) ltot = 0;
    __syncthreads();

    auto emit = [&](uint32_t e, float v) {
        uint32_t c = e % (uint32_t)C_;
        if (c < NCLS) {
            uint32_t nl = e / (uint32_t)C_;
            int q = atomicAdd(&ltot, 1);
            atomicAdd(&lhist[c], 1);
            if (q < CAPB)
                stage[q] = make_uint2(__float_as_uint(v), (c << 16) | nl);
        }
    };
    auto proc4 = [&](float4 x, uint32_t q) {
        if (x.x >= THR_F || x.y >= THR_F || x.z >= THR_F || x.w >= THR_F) {
            uint32_t e = q * 4u;
            if (x.x >= THR_F) emit(e + 0u, x.x);
            if (x.y >= THR_F) emit(e + 1u, x.y);
            if (x.z >= THR_F) emit(e + 2u, x.z);
            if (x.w >= THR_F) emit(e + 3u, x.w);
        }
    };

    uint32_t qb = (uint32_t)tid;
#pragma unroll 1
    for (int s = 0; s < 5; ++s, qb += 8 * NTH) {
        float4 v[8];
#pragma unroll
        for (int u = 0; u < 8; ++u) v[u] = slab[qb + u * NTH];
#pragma unroll
        for (int u = 0; u < 8; ++u) proc4(v[u], qb + u * NTH);
    }
    if (tid < SLAB_F4 - 5 * 8 * NTH) {
        uint32_t q = 5u * 8u * NTH + (uint32_t)tid;
        proc4(slab[q], q);
    }
    __syncthreads();

    const int tot = ltot;
    if (tot > CAPB) {                      // statistically never: force slow path
        for (int k = tid; k < NCLS; k += NTH)
            atomicAdd(&cnt[b * NCLS + k], CAP2 + 1);
        return;
    }
    if (tid < NCLS)
        gbase[tid] = atomicAdd(&cnt[b * NCLS + tid], lhist[tid]);
    __syncthreads();

    for (int q = tid; q < tot; q += NTH) {
        uint2 s = stage[q];
        uint32_t c  = s.y >> 16;
        uint32_t nl = s.y & 0xFFFFu;
        int pos = atomicAdd(&lpos[c], 1);
        int dst = gbase[c] + pos;
        if (dst < CAP2)
            cand[(size_t)(b * NCLS + c) * CAP2 + dst] = make_uint2(s.x, n0 + nl);
    }
}

// ---- select LDS: phase-disjoint overlays (total 16048 B -> 8 blocks/CU) ----
// region A [0,8000):    surv uint2[768] -> sup u64[200][5] -> ostage f32[1200]
// region B [8000,14400): hist int[256 fast | 1024 slow] -> box f4[200] + cor f4[200]
#define SUPS      5                      // padded u64 row stride (bank spread)
#define SM_A      0
#define SM_B      8000
#define SM_BOX    8000
#define SM_COR    11200
#define SM_TVAL   14400                  // float[TOPK]
#define SM_TIDX   15200                  // int[TOPK]
#define SM_CTRL   16000                  // int[4]: [1]=cutoff [2]=nsurv
#define SM_KEEPW  16016                  // u64[4]
#define SM_TOTAL  16048

__global__ __launch_bounds__(NTH) void select_nms_k(const float* __restrict__ conf,
                                                    const float* __restrict__ loc,
                                                    const int* __restrict__ cnt,
                                                    const uint2* __restrict__ cand,
                                                    float* __restrict__ out,
                                                    int use_ws) {
#pragma clang fp contract(off)
    const int bc   = blockIdx.x;
    const int b    = bc / NCLS;
    const int c    = bc - b * NCLS;
    const int tid  = threadIdx.x;
    const int lane = tid & 63;
    const int wv   = tid >> 6;

    __shared__ __align__(16) char smem[SM_TOTAL];
    uint2*  surv   = (uint2*)(smem + SM_A);
    unsigned long long* sup = (unsigned long long*)(smem + SM_A);
    float*  ostage = (float*)(smem + SM_A);
    int*    hist   = (int*)(smem + SM_B);
    float4* box_s  = (float4*)(smem + SM_BOX);
    float4* cor_s  = (float4*)(smem + SM_COR);
    float*  top_val = (float*)(smem + SM_TVAL);
    int*    top_idx = (int*)(smem + SM_TIDX);
    int*    ctrl   = (int*)(smem + SM_CTRL);
    unsigned long long* keepw = (unsigned long long*)(smem + SM_KEEPW);

    int M = use_ws ? cnt[bc] : 0;
    const bool fast = use_ws && (M >= TOPK) && (M <= CAP2);
    int S = 0;

    if (fast) {
        // phase 1: candidates -> registers (static slots; M <= 3*NTH), init
        const uint2* src = cand + (size_t)bc * CAP2;
        uint2 my0 = make_uint2(0u, 0u), my1 = make_uint2(0u, 0u), my2 = make_uint2(0u, 0u);
        if (tid           < M) my0 = src[tid];
        if (tid +     NTH < M) my1 = src[tid + NTH];
        if (tid + 2 * NTH < M) my2 = src[tid + 2 * NTH];
        hist[tid] = 0;                               // NTH == 256 buckets
        if (tid == 0) ctrl[2] = 0;
        __syncthreads();

        // phase 2: histogram from registers (val==0 sentinels excluded by guards)
        if (tid           < M) { uint32_t k = (my0.x - THR_BITS) >> 10; atomicAdd(&hist[k > 255u ? 255u : k], 1); }
        if (tid +     NTH < M) { uint32_t k = (my1.x - THR_BITS) >> 10; atomicAdd(&hist[k > 255u ? 255u : k], 1); }
        if (tid + 2 * NTH < M) { uint32_t k = (my2.x - THR_BITS) >> 10; atomicAdd(&hist[k > 255u ? 255u : k], 1); }
        __syncthreads();

        // phase 3: wave-0 parallel suffix scan (lane 0 = topmost 4 buckets)
        if (tid < 64) {
            int4 h = ((const int4*)hist)[63 - tid];
            int s3 = h.w, s2 = s3 + h.z, s1 = s2 + h.y, s0 = s1 + h.x;
            int tot = s0;
#pragma unroll
            for (int d = 1; d < 64; d <<= 1) {
                int t = __shfl_up(tot, d);
                if (tid >= d) tot += t;
            }
            int before = tot - s0;                   // count strictly above this lane
            if (before < TOPK && before + s0 >= TOPK) {   // unique hit lane
                int inner = (before + s3 >= TOPK) ? 3 : (before + s2 >= TOPK) ? 2
                          : (before + s1 >= TOPK) ? 1 : 0;
                ctrl[1] = (63 - tid) * 4 + inner;
            }
        }
        __syncthreads();

        // phase 4: prefill (hist dead) + ballot-compact survivors
        if (tid < TOPK) {
            top_idx[tid] = -1;
            box_s[tid] = make_float4(-1.f, -1.f, -1.f, -1.f);
            cor_s[tid] = make_float4(0.f, 0.f, 0.f, 0.f);
        }
        const uint32_t edge = THR_BITS + ((uint32_t)ctrl[1] << 10);
#define COMPACT(MY)                                                          \
        {                                                                    \
            bool take = (MY.x >= edge);                                      \
            unsigned long long mask = __ballot(take);                        \
            int base = 0;                                                    \
            if (lane == 0 && mask) base = atomicAdd(&ctrl[2], (int)__popcll(mask)); \
            base = __shfl(base, 0);                                          \
            if (take) {                                                      \
                int pos = base + (int)__popcll(mask & ((1ull << lane) - 1ull)); \
                if (pos < CAP2) surv[pos] = MY;                              \
            }                                                                \
        }
        COMPACT(my0) COMPACT(my1) COMPACT(my2)
#undef COMPACT
        __syncthreads();
        S = min(ctrl[2], CAP2);
    } else {
        // ---- slow path: strided re-read of conf (robust fallback, unused here) ----
        for (int k = tid; k < HBUCK; k += NTH) hist[k] = 0;
        if (tid == 0) ctrl[2] = 0;
        __syncthreads();
        const float* col = conf + ((size_t)b * N_) * C_ + c;
        for (int n = tid; n < N_; n += NTH) {
            float v = col[(size_t)n * C_];
            if (v >= 0.5f) {
                int bkt = (int)(__float_as_uint(v) >> 13) - HBASE;
                atomicAdd(&hist[min(bkt, HBUCK - 1)], 1);
            }
        }
        __syncthreads();
        if (tid == 0) {
            int acc = 0, cut = -1;
            for (int k = HBUCK - 1; k >= 0; --k) {
                acc += hist[k];
                if (acc >= TOPK) { cut = k; break; }
            }
            ctrl[1] = cut;
        }
        __syncthreads();
        const int   cutv = ctrl[1];
        const float vcut = (cutv >= 0) ? __uint_as_float((uint32_t)(HBASE + cutv) << 13)
                                       : CONF_T;
        for (int n = tid; n < N_; n += NTH) {
            float v = col[(size_t)n * C_];
            bool take = (cutv >= 0) ? (v >= vcut) : (v > CONF_T);
            if (take) {
                int p = atomicAdd(&ctrl[2], 1);
                if (p < CAP2) surv[p] = make_uint2(__float_as_uint(v), (uint32_t)n);
            }
        }
        __syncthreads();                 // gather done; hist dead
        if (tid < TOPK) {
            top_idx[tid] = -1;
            box_s[tid] = make_float4(-1.f, -1.f, -1.f, -1.f);
            cor_s[tid] = make_float4(0.f, 0.f, 0.f, 0.f);
        }
        S = min(ctrl[2], CAP2);
        __syncthreads();                 // prefill visible before rank writes
    }

    // ---- rank among survivors (exact: val desc, idx asc) + fused loc gather ----
    for (int i = tid; i < S; i += NTH) {
        uint2 me = surv[i];
        int rank = 0;
#pragma unroll 4
        for (int j = 0; j < S; ++j) {
            uint2 cj = surv[j];
            rank += (cj.x > me.x) || (cj.x == me.x && (int)cj.y < (int)me.y);
        }
        if (rank < TOPK) {
            top_val[rank] = __uint_as_float(me.x);
            top_idx[rank] = (int)me.y;
            float4 bx = *(const float4*)(loc + ((size_t)b * N_ + (size_t)(int)me.y) * 4);
            float hw = bx.z * 0.5f;
            float hh = bx.w * 0.5f;
            box_s[rank] = bx;
            cor_s[rank] = make_float4(bx.x - hw, bx.y - hh, bx.x + hw, bx.y + hh);
        }
    }
    __syncthreads();                     // surv dead; sup may overlay region A

    {   // keep-init: one ballot per wave
        bool v = (tid < TOPK) && (top_idx[tid] >= 0);
        unsigned long long m = __ballot(v);
        if (lane == 0) keepw[wv] = m;
    }

    {   // suppression bitmask: wave w owns 64-column word w of every row
        const int j = tid;
        float4 d = make_float4(0.f, 0.f, 0.f, 0.f);
        const bool jv = (j < TOPK);
        if (jv) d = cor_s[j];
        const float areaB = (d.z - d.x) * (d.w - d.y);
#pragma unroll 2
        for (int i = 0; i < TOPK; ++i) {
            float4 a = cor_s[i];
            bool s = false;
            if (jv && j > i) {
                float ltx = fmaxf(a.x, d.x), lty = fmaxf(a.y, d.y);
                float rbx = fminf(a.z, d.z), rby = fminf(a.w, d.w);
                float w  = fmaxf(rbx - ltx, 0.0f);
                float h  = fmaxf(rby - lty, 0.0f);
                float inter = w * h;
                float areaA = (a.z - a.x) * (a.w - a.y);
                float iou = inter / (areaA + areaB - inter);
                s = iou > IOU_T;
            }
            unsigned long long m = __ballot(s);
            if (lane == 0) sup[i * SUPS + wv] = m;
        }
    }
    __syncthreads();

    // greedy scan in wave 0 registers: lane l holds rows l, 64+l, 128+l, 192+l
    if (tid < 64) {
        unsigned long long r0[4], r1[4], r2[4], r3[4];
#pragma unroll
        for (int w = 0; w < 4; ++w) {
            r0[w] = sup[(0 * 64 + tid) * SUPS + w];
            r1[w] = sup[(1 * 64 + tid) * SUPS + w];
            r2[w] = sup[(2 * 64 + tid) * SUPS + w];
            r3[w] = (192 + tid < TOPK) ? sup[(192 + tid) * SUPS + w] : 0ull;
        }
        unsigned long long k0 = keepw[0], k1 = keepw[1], k2 = keepw[2], k3 = keepw[3];
#define GREEDY_BLK(KW, RR)                                            \
        for (int ii = 0; ii < 64; ++ii) {                             \
            if ((KW >> ii) & 1ull) {                                  \
                k0 &= ~__shfl(RR[0], ii);                             \
                k1 &= ~__shfl(RR[1], ii);                             \
                k2 &= ~__shfl(RR[2], ii);                             \
                k3 &= ~__shfl(RR[3], ii);                             \
            }                                                         \
        }
        GREEDY_BLK(k0, r0)
        GREEDY_BLK(k1, r1)
        GREEDY_BLK(k2, r2)
        GREEDY_BLK(k3, r3)
#undef GREEDY_BLK
        if (tid == 0) { keepw[0] = k0; keepw[1] = k1; keepw[2] = k2; keepw[3] = k3; }
    }
    __syncthreads();                     // sup dead; ostage may overlay region A

    // stage 200x6 floats in LDS, flush as 300 coalesced float4
    if (tid < TOPK) {
        const bool kp = (keepw[tid >> 6] >> (tid & 63)) & 1ull;
        float4 bx = box_s[tid];
        float* o = ostage + tid * 6;
        if (kp) {
            o[0] = (float)c;   o[1] = top_val[tid];
            o[2] = bx.x; o[3] = bx.y; o[4] = bx.z; o[5] = bx.w;
        } else {
            o[0] = -1.f; o[1] = -1.f; o[2] = -1.f;
            o[3] = -1.f; o[4] = -1.f; o[5] = -1.f;
        }
        out[(size_t)NBC * TOPK * 6 + (size_t)bc * TOPK + tid] = kp ? 1.0f : 0.0f;
    }
    __syncthreads();
    {
        float4* dst = (float4*)(out + (size_t)bc * TOPK * 6);
        const float4* src4 = (const float4*)ostage;
        for (int k = tid; k < TOPK * 6 / 4; k += NTH) dst[k] = src4[k];
    }
}

extern "C" void kernel_launch(void* const* d_in, const int* in_sizes, int n_in,
                              void* d_out, int out_size, void* d_ws, size_t ws_size,
                              hipStream_t stream) {
    (void)in_sizes; (void)n_in; (void)out_size;
    const float* loc  = (const float*)d_in[0];
    const float* conf = (const float*)d_in[1];
    float* out = (float*)d_out;

    const bool use_ws = (d_ws != nullptr) && (ws_size >= WS_NEED);
    int*   cnt  = (int*)((char*)d_ws + OFF_CNT);
    uint2* cand = (uint2*)((char*)d_ws + OFF_CAND);

    if (use_ws) {
        hipLaunchKernelGGL(zero_cnt, dim3((NBC + NTH - 1) / NTH), dim3(NTH), 0, stream, cnt);
        hipLaunchKernelGGL(filter_k, dim3(B_ * NCHUNK), dim3(NTH), 0, stream,
                           conf, cnt, cand);
    }
    hipLaunchKernelGGL(select_nms_k, dim3(NBC), dim3(NTH), 0, stream,
                       conf, loc, cnt, cand, out, use_ws ? 1 : 0);
}

// Round 6
// 210.166 us; speedup vs baseline: 5.6634x; 1.1367x over previous
//
#include <hip/hip_runtime.h>
#include <cstdint>

#define B_      32
#define N_      32768
#define C_      81
#define NCLS    80      // last class (background) skipped
#define TOPK    200
#define CONF_T  0.01f
#define IOU_T   0.45f
#define NTH     256
#define NBC     (B_ * NCLS)          // 2560 (b,c) tasks

// exact IoU threshold compare without div:
// fl(inter/U) > 0.45f  <=>  (double)inter > M_IOU * (double)U   (U >= 0)
// M_IOU = midpoint(0.45f, nextafterf(0.45f)) as double; M*U exact in f64.
#define M_IOU   0.450000017881393432617187500

// ---- fast-path pre-filter: THR = 1 - 2^-6 = 0.984375 ----
// P(v >= THR) = 1/64 -> per-(b,c) count ~ Binom(32768,1/64): mean 512, sd 22.6.
// [TOPK, CAP2] = [200,768] is [-13.8sd, +11.3sd] -> fast path essentially always.
#define THR_F    0.984375f
#define THR_BITS 0x3F7C0000u         // bits(0.984375); [THR,1.0) spans 2^18 codes
#define CAP2     768

// filter blocking: one block per (b, 512-anchor slab)
#define ANCH_PB  512
#define NCHUNK   (N_ / ANCH_PB)      // 64
#define SLAB_F4  (ANCH_PB * C_ / 4)  // 10368 float4 per block
#define CAPB     1024                // LDS staging (mean 648, sd 25.3 -> +14.9sd)

// slow-path histogram buckets over [0.5,1.0) via float bits
#define HBASE   129024
#define HBUCK   1024

// ws layout (bytes): cnt[NBC] then cand[NBC][CAP2] as uint2(val_bits, anchor)
#define OFF_CNT  0
#define OFF_CAND 16384
#define WS_NEED  (OFF_CAND + (size_t)NBC * CAP2 * 8)

__global__ void zero_cnt(int* __restrict__ cnt) {
    int i = blockIdx.x * blockDim.x + threadIdx.x;
    if (i < NBC) cnt[i] = 0;
}

// One block per (b, 512-anchor slab): coalesced contiguous read, LDS-staged
// candidates, one global atomic per class per block.  (At HBM roofline - frozen.)
__global__ __launch_bounds__(NTH) void filter_k(const float* __restrict__ conf,
                                                int* __restrict__ cnt,
                                                uint2* __restrict__ cand) {
    const int tid   = threadIdx.x;
    const int blk   = blockIdx.x;
    const int b     = blk >> 6;           // NCHUNK == 64
    const int chunk = blk & (NCHUNK - 1);
    const uint32_t n0 = (uint32_t)chunk * ANCH_PB;
    const float4* slab = (const float4*)(conf + ((size_t)b * N_ + n0) * C_);

    __shared__ uint2 stage[CAPB];
    __shared__ int   lhist[NCLS];
    __shared__ int   lpos[NCLS];
    __shared__ int   gbase[NCLS];
    __shared__ int   ltot;

    for (int k = tid; k < NCLS; k += NTH) { lhist[k] = 0; lpos[k] = 0; }
    if (tid == 0) ltot = 0;
    __syncthreads();

    auto emit = [&](uint32_t e, float v) {
        uint32_t c = e % (uint32_t)C_;
        if (c < NCLS) {
            uint32_t nl = e / (uint32_t)C_;
            int q = atomicAdd(&ltot, 1);
            atomicAdd(&lhist[c], 1);
            if (q < CAPB)
                stage[q] = make_uint2(__float_as_uint(v), (c << 16) | nl);
        }
    };
    auto proc4 = [&](float4 x, uint32_t q) {
        if (x.x >= THR_F || x.y >= THR_F || x.z >= THR_F || x.w >= THR_F) {
            uint32_t e = q * 4u;
            if (x.x >= THR_F) emit(e + 0u, x.x);
            if (x.y >= THR_F) emit(e + 1u, x.y);
            if (x.z >= THR_F) emit(e + 2u, x.z);
            if (x.w >= THR_F) emit(e + 3u, x.w);
        }
    };

    uint32_t qb = (uint32_t)tid;
#pragma unroll 1
    for (int s = 0; s < 5; ++s, qb += 8 * NTH) {
        float4 v[8];
#pragma unroll
        for (int u = 0; u < 8; ++u) v[u] = slab[qb + u * NTH];
#pragma unroll
        for (int u = 0; u < 8; ++u) proc4(v[u], qb + u * NTH);
    }
    if (tid < SLAB_F4 - 5 * 8 * NTH) {
        uint32_t q = 5u * 8u * NTH + (uint32_t)tid;
        proc4(slab[q], q);
    }
    __syncthreads();

    const int tot = ltot;
    if (tot > CAPB) {                      // statistically never: force slow path
        for (int k = tid; k < NCLS; k += NTH)
            atomicAdd(&cnt[b * NCLS + k], CAP2 + 1);
        return;
    }
    if (tid < NCLS)
        gbase[tid] = atomicAdd(&cnt[b * NCLS + tid], lhist[tid]);
    __syncthreads();

    for (int q = tid; q < tot; q += NTH) {
        uint2 s = stage[q];
        uint32_t c  = s.y >> 16;
        uint32_t nl = s.y & 0xFFFFu;
        int pos = atomicAdd(&lpos[c], 1);
        int dst = gbase[c] + pos;
        if (dst < CAP2)
            cand[(size_t)(b * NCLS + c) * CAP2 + dst] = make_uint2(s.x, n0 + nl);
    }
}

// ---- select LDS: phase-disjoint overlays ----
// region A [0,8000):    surv u64-key[768] -> sup u64[200][5] -> ostage f32[1200]
// region B [8000,14400): hist int[256 fast | 1024 slow] -> box f4[200] + cor f4[200]
// surv key = (val_bits<<32) | ~anchor : (val desc, idx asc) == u64 desc, keys unique
#define SUPS      5                      // padded u64 row stride (bank spread)
#define SM_A      0
#define SM_B      8000
#define SM_BOX    8000
#define SM_COR    11200
#define SM_TVAL   14400                  // float[TOPK]
#define SM_TIDX   15200                  // int[TOPK]
#define SM_CTRL   16000                  // int[4]: [1]=cutoff [2]=nsurv
#define SM_KEEPW  16016                  // u64[4]
#define SM_AREA   16048                  // float[TOPK]
#define SM_TOTAL  16848

__global__ __launch_bounds__(NTH) void select_nms_k(const float* __restrict__ conf,
                                                    const float* __restrict__ loc,
                                                    const int* __restrict__ cnt,
                                                    const uint2* __restrict__ cand,
                                                    float* __restrict__ out,
                                                    int use_ws) {
#pragma clang fp contract(off)
    const int bc   = blockIdx.x;
    const int b    = bc / NCLS;
    const int c    = bc - b * NCLS;
    const int tid  = threadIdx.x;
    const int lane = tid & 63;
    const int wv   = tid >> 6;

    __shared__ __align__(16) char smem[SM_TOTAL];
    unsigned long long* surv = (unsigned long long*)(smem + SM_A);
    unsigned long long* sup  = (unsigned long long*)(smem + SM_A);
    float*  ostage = (float*)(smem + SM_A);
    int*    hist   = (int*)(smem + SM_B);
    float4* box_s  = (float4*)(smem + SM_BOX);
    float4* cor_s  = (float4*)(smem + SM_COR);
    float*  top_val = (float*)(smem + SM_TVAL);
    int*    top_idx = (int*)(smem + SM_TIDX);
    int*    ctrl   = (int*)(smem + SM_CTRL);
    unsigned long long* keepw = (unsigned long long*)(smem + SM_KEEPW);
    float*  area_s = (float*)(smem + SM_AREA);

    int M = use_ws ? cnt[bc] : 0;
    const bool fast = use_ws && (M >= TOPK) && (M <= CAP2);
    int S = 0;

    if (fast) {
        // phase 1: candidates -> registers (static slots; M <= 3*NTH), init
        const uint2* src = cand + (size_t)bc * CAP2;
        uint2 my0 = make_uint2(0u, 0u), my1 = make_uint2(0u, 0u), my2 = make_uint2(0u, 0u);
        if (tid           < M) my0 = src[tid];
        if (tid +     NTH < M) my1 = src[tid + NTH];
        if (tid + 2 * NTH < M) my2 = src[tid + 2 * NTH];
        hist[tid] = 0;                               // NTH == 256 buckets
        if (tid == 0) ctrl[2] = 0;
        __syncthreads();

        // phase 2: histogram from registers
        if (tid           < M) { uint32_t k = (my0.x - THR_BITS) >> 10; atomicAdd(&hist[k > 255u ? 255u : k], 1); }
        if (tid +     NTH < M) { uint32_t k = (my1.x - THR_BITS) >> 10; atomicAdd(&hist[k > 255u ? 255u : k], 1); }
        if (tid + 2 * NTH < M) { uint32_t k = (my2.x - THR_BITS) >> 10; atomicAdd(&hist[k > 255u ? 255u : k], 1); }
        __syncthreads();

        // phase 3: wave-0 parallel suffix scan (lane 0 = topmost 4 buckets)
        if (tid < 64) {
            int4 h = ((const int4*)hist)[63 - tid];
            int s3 = h.w, s2 = s3 + h.z, s1 = s2 + h.y, s0 = s1 + h.x;
            int tot = s0;
#pragma unroll
            for (int d = 1; d < 64; d <<= 1) {
                int t = __shfl_up(tot, d);
                if (tid >= d) tot += t;
            }
            int before = tot - s0;                   // count strictly above this lane
            if (before < TOPK && before + s0 >= TOPK) {   // unique hit lane
                int inner = (before + s3 >= TOPK) ? 3 : (before + s2 >= TOPK) ? 2
                          : (before + s1 >= TOPK) ? 1 : 0;
                ctrl[1] = (63 - tid) * 4 + inner;
            }
        }
        __syncthreads();

        // phase 4: prefill (hist dead) + ballot-compact survivors (as u64 keys)
        if (tid < TOPK) {
            top_idx[tid] = -1;
            area_s[tid] = 0.0f;
            box_s[tid] = make_float4(-1.f, -1.f, -1.f, -1.f);
            cor_s[tid] = make_float4(0.f, 0.f, 0.f, 0.f);
        }
        const uint32_t edge = THR_BITS + ((uint32_t)ctrl[1] << 10);
#define COMPACT(MY)                                                          \
        {                                                                    \
            bool take = (MY.x >= edge);                                      \
            unsigned long long mask = __ballot(take);                        \
            int base = 0;                                                    \
            if (lane == 0 && mask) base = atomicAdd(&ctrl[2], (int)__popcll(mask)); \
            base = __shfl(base, 0);                                          \
            if (take) {                                                      \
                int pos = base + (int)__popcll(mask & ((1ull << lane) - 1ull)); \
                if (pos < CAP2)                                              \
                    surv[pos] = ((unsigned long long)MY.x << 32) | (uint32_t)(~MY.y); \
            }                                                                \
        }
        COMPACT(my0) COMPACT(my1) COMPACT(my2)
#undef COMPACT
        __syncthreads();
        S = min(ctrl[2], CAP2);
    } else {
        // ---- slow path: strided re-read of conf (robust fallback, unused here) ----
        for (int k = tid; k < HBUCK; k += NTH) hist[k] = 0;
        if (tid == 0) ctrl[2] = 0;
        __syncthreads();
        const float* col = conf + ((size_t)b * N_) * C_ + c;
        for (int n = tid; n < N_; n += NTH) {
            float v = col[(size_t)n * C_];
            if (v >= 0.5f) {
                int bkt = (int)(__float_as_uint(v) >> 13) - HBASE;
                atomicAdd(&hist[min(bkt, HBUCK - 1)], 1);
            }
        }
        __syncthreads();
        if (tid == 0) {
            int acc = 0, cut = -1;
            for (int k = HBUCK - 1; k >= 0; --k) {
                acc += hist[k];
                if (acc >= TOPK) { cut = k; break; }
            }
            ctrl[1] = cut;
        }
        __syncthreads();
        const int   cutv = ctrl[1];
        const float vcut = (cutv >= 0) ? __uint_as_float((uint32_t)(HBASE + cutv) << 13)
                                       : CONF_T;
        for (int n = tid; n < N_; n += NTH) {
            float v = col[(size_t)n * C_];
            bool take = (cutv >= 0) ? (v >= vcut) : (v > CONF_T);
            if (take) {
                int p = atomicAdd(&ctrl[2], 1);
                if (p < CAP2)
                    surv[p] = ((unsigned long long)__float_as_uint(v) << 32)
                            | (uint32_t)(~(uint32_t)n);
            }
        }
        __syncthreads();                 // gather done; hist dead
        if (tid < TOPK) {
            top_idx[tid] = -1;
            area_s[tid] = 0.0f;
            box_s[tid] = make_float4(-1.f, -1.f, -1.f, -1.f);
            cor_s[tid] = make_float4(0.f, 0.f, 0.f, 0.f);
        }
        S = min(ctrl[2], CAP2);
        __syncthreads();                 // prefill visible before rank writes
    }

    // ---- rank among survivors (u64 keys: exact val desc, idx asc) + loc gather ----
    for (int i = tid; i < S; i += NTH) {
        unsigned long long me = surv[i];
        int rank = 0;
#pragma unroll 4
        for (int j = 0; j < S; ++j)
            rank += (surv[j] > me);
        if (rank < TOPK) {
            int idx = (int)(~(uint32_t)me);
            top_val[rank] = __uint_as_float((uint32_t)(me >> 32));
            top_idx[rank] = idx;
            float4 bx = *(const float4*)(loc + ((size_t)b * N_ + (size_t)idx) * 4);
            float hw = bx.z * 0.5f;
            float hh = bx.w * 0.5f;
            float4 cr = make_float4(bx.x - hw, bx.y - hh, bx.x + hw, bx.y + hh);
            box_s[rank] = bx;
            cor_s[rank] = cr;
            area_s[rank] = (cr.z - cr.x) * (cr.w - cr.y);
        }
    }
    __syncthreads();                     // surv dead; sup may overlay region A

    {   // keep-init: one ballot per wave
        bool v = (tid < TOPK) && (top_idx[tid] >= 0);
        unsigned long long m = __ballot(v);
        if (lane == 0) keepw[wv] = m;
    }

    {   // suppression bitmask: wave w owns 64-column word w of every row
        const int j = tid;
        float4 d = make_float4(0.f, 0.f, 0.f, 0.f);
        float  areaB = 0.0f;
        const bool jv = (j < TOPK);
        if (jv) { d = cor_s[j]; areaB = area_s[j]; }
#pragma unroll 2
        for (int i = 0; i < TOPK; ++i) {
            float4 a = cor_s[i];
            bool s = false;
            if (jv && j > i) {
                float ltx = fmaxf(a.x, d.x), lty = fmaxf(a.y, d.y);
                float rbx = fminf(a.z, d.z), rby = fminf(a.w, d.w);
                float w  = fmaxf(rbx - ltx, 0.0f);
                float h  = fmaxf(rby - lty, 0.0f);
                float inter = w * h;
                float U = (area_s[i] + areaB) - inter;
                // exact: fl(inter/U) > 0.45f  <=>  inter_d > M_IOU*U_d  (U>=0)
                s = ((double)inter > M_IOU * (double)U);
            }
            unsigned long long m = __ballot(s);
            if (lane == 0) sup[i * SUPS + wv] = m;
        }
    }
    __syncthreads();

    // greedy scan in wave 0 registers: lane l holds rows l, 64+l, 128+l, 192+l
    if (tid < 64) {
        unsigned long long r0[4], r1[4], r2[4], r3[4];
#pragma unroll
        for (int w = 0; w < 4; ++w) {
            r0[w] = sup[(0 * 64 + tid) * SUPS + w];
            r1[w] = sup[(1 * 64 + tid) * SUPS + w];
            r2[w] = sup[(2 * 64 + tid) * SUPS + w];
            r3[w] = (192 + tid < TOPK) ? sup[(192 + tid) * SUPS + w] : 0ull;
        }
        unsigned long long k0 = keepw[0], k1 = keepw[1], k2 = keepw[2], k3 = keepw[3];
#define GREEDY_BLK(KW, RR)                                            \
        for (int ii = 0; ii < 64; ++ii) {                             \
            if ((KW >> ii) & 1ull) {                                  \
                k0 &= ~__shfl(RR[0], ii);                             \
                k1 &= ~__shfl(RR[1], ii);                             \
                k2 &= ~__shfl(RR[2], ii);                             \
                k3 &= ~__shfl(RR[3], ii);                             \
            }                                                         \
        }
        GREEDY_BLK(k0, r0)
        GREEDY_BLK(k1, r1)
        GREEDY_BLK(k2, r2)
        GREEDY_BLK(k3, r3)
#undef GREEDY_BLK
        if (tid == 0) { keepw[0] = k0; keepw[1] = k1; keepw[2] = k2; keepw[3] = k3; }
    }
    __syncthreads();                     // sup dead; ostage may overlay region A

    // stage 200x6 floats in LDS, flush as 300 coalesced float4
    if (tid < TOPK) {
        const bool kp = (keepw[tid >> 6] >> (tid & 63)) & 1ull;
        float4 bx = box_s[tid];
        float* o = ostage + tid * 6;
        if (kp) {
            o[0] = (float)c;   o[1] = top_val[tid];
            o[2] = bx.x; o[3] = bx.y; o[4] = bx.z; o[5] = bx.w;
        } else {
            o[0] = -1.f; o[1] = -1.f; o[2] = -1.f;
            o[3] = -1.f; o[4] = -1.f; o[5] = -1.f;
        }
        out[(size_t)NBC * TOPK * 6 + (size_t)bc * TOPK + tid] = kp ? 1.0f : 0.0f;
    }
    __syncthreads();
    {
        float4* dst = (float4*)(out + (size_t)bc * TOPK * 6);
        const float4* src4 = (const float4*)ostage;
        for (int k = tid; k < TOPK * 6 / 4; k += NTH) dst[k] = src4[k];
    }
}

extern "C" void kernel_launch(void* const* d_in, const int* in_sizes, int n_in,
                              void* d_out, int out_size, void* d_ws, size_t ws_size,
                              hipStream_t stream) {
    (void)in_sizes; (void)n_in; (void)out_size;
    const float* loc  = (const float*)d_in[0];
    const float* conf = (const float*)d_in[1];
    float* out = (float*)d_out;

    const bool use_ws = (d_ws != nullptr) && (ws_size >= WS_NEED);
    int*   cnt  = (int*)((char*)d_ws + OFF_CNT);
    uint2* cand = (uint2*)((char*)d_ws + OFF_CAND);

    if (use_ws) {
        hipLaunchKernelGGL(zero_cnt, dim3((NBC + NTH - 1) / NTH), dim3(NTH), 0, stream, cnt);
        hipLaunchKernelGGL(filter_k, dim3(B_ * NCHUNK), dim3(NTH), 0, stream,
                           conf, cnt, cand);
    }
    hipLaunchKernelGGL(select_nms_k, dim3(NBC), dim3(NTH), 0, stream,
                       conf, loc, cnt, cand, out, use_ws ? 1 : 0);
}

// Round 7
// 144.399 us; speedup vs baseline: 8.2427x; 1.4555x over previous
//
#include <hip/hip_runtime.h>
#include <cstdint>

#define B_      32
#define N_      32768
#define C_      81
#define NCLS    80      // last class (background) skipped
#define TOPK    200
#define CONF_T  0.01f
#define IOU_T   0.45f
#define NTH     256
#define NBC     (B_ * NCLS)          // 2560 (b,c) tasks

// exact IoU threshold compare without div:
// fl(inter/U) > 0.45f  <=>  (double)inter > M_IOU * (double)U   (U >= 0)
#define M_IOU   0.450000017881393432617187500

// ---- fast-path pre-filter: THR = 1 - 2^-6 = 0.984375 ----
#define THR_F    0.984375f
#define THR_BITS 0x3F7C0000u
#define CAP2     768

// filter blocking: one block per (b, 512-anchor slab)
#define ANCH_PB  512
#define NCHUNK   (N_ / ANCH_PB)      // 64
#define SLAB_F4  (ANCH_PB * C_ / 4)  // 10368 float4 per block
#define CAPB     1024

// slow-path histogram buckets over [0.5,1.0) via float bits
#define HBASE   129024
#define HBUCK   1024

// per-wave fast path: survivor cap (S in [200,256] expected; punt otherwise)
#define SCAP    256

// ws layout (bytes): cnt[NBC] | flags[NBC] | cand[NBC][CAP2] uint2
#define OFF_CNT   0
#define OFF_FLAGS 16384
#define OFF_CAND  32768
#define WS_NEED  (OFF_CAND + (size_t)NBC * CAP2 * 8)

#define WAVE_LGKM() asm volatile("s_waitcnt lgkmcnt(0)" ::: "memory")

__global__ void zero_hdr(int* __restrict__ p) {      // zeros cnt+flags region
    int i = blockIdx.x * blockDim.x + threadIdx.x;
    if (i < 8192) p[i] = 0;
}

// ---- filter: at HBM roofline, frozen since R4 ----
__global__ __launch_bounds__(NTH) void filter_k(const float* __restrict__ conf,
                                                int* __restrict__ cnt,
                                                uint2* __restrict__ cand) {
    const int tid   = threadIdx.x;
    const int blk   = blockIdx.x;
    const int b     = blk >> 6;
    const int chunk = blk & (NCHUNK - 1);
    const uint32_t n0 = (uint32_t)chunk * ANCH_PB;
    const float4* slab = (const float4*)(conf + ((size_t)b * N_ + n0) * C_);

    __shared__ uint2 stage[CAPB];
    __shared__ int   lhist[NCLS];
    __shared__ int   lpos[NCLS];
    __shared__ int   gbase[NCLS];
    __shared__ int   ltot;

    for (int k = tid; k < NCLS; k += NTH) { lhist[k] = 0; lpos[k] = 0; }
    if (tid == 0) ltot = 0;
    __syncthreads();

    auto emit = [&](uint32_t e, float v) {
        uint32_t c = e % (uint32_t)C_;
        if (c < NCLS) {
            uint32_t nl = e / (uint32_t)C_;
            int q = atomicAdd(&ltot, 1);
            atomicAdd(&lhist[c], 1);
            if (q < CAPB)
                stage[q] = make_uint2(__float_as_uint(v), (c << 16) | nl);
        }
    };
    auto proc4 = [&](float4 x, uint32_t q) {
        if (x.x >= THR_F || x.y >= THR_F || x.z >= THR_F || x.w >= THR_F) {
            uint32_t e = q * 4u;
            if (x.x >= THR_F) emit(e + 0u, x.x);
            if (x.y >= THR_F) emit(e + 1u, x.y);
            if (x.z >= THR_F) emit(e + 2u, x.z);
            if (x.w >= THR_F) emit(e + 3u, x.w);
        }
    };

    uint32_t qb = (uint32_t)tid;
#pragma unroll 1
    for (int s = 0; s < 5; ++s, qb += 8 * NTH) {
        float4 v[8];
#pragma unroll
        for (int u = 0; u < 8; ++u) v[u] = slab[qb + u * NTH];
#pragma unroll
        for (int u = 0; u < 8; ++u) proc4(v[u], qb + u * NTH);
    }
    if (tid < SLAB_F4 - 5 * 8 * NTH) {
        uint32_t q = 5u * 8u * NTH + (uint32_t)tid;
        proc4(slab[q], q);
    }
    __syncthreads();

    const int tot = ltot;
    if (tot > CAPB) {
        for (int k = tid; k < NCLS; k += NTH)
            atomicAdd(&cnt[b * NCLS + k], CAP2 + 1);
        return;
    }
    if (tid < NCLS)
        gbase[tid] = atomicAdd(&cnt[b * NCLS + tid], lhist[tid]);
    __syncthreads();

    for (int q = tid; q < tot; q += NTH) {
        uint2 s = stage[q];
        uint32_t c  = s.y >> 16;
        uint32_t nl = s.y & 0xFFFFu;
        int pos = atomicAdd(&lpos[c], 1);
        int dst = gbase[c] + pos;
        if (dst < CAP2)
            cand[(size_t)(b * NCLS + c) * CAP2 + dst] = make_uint2(s.x, n0 + nl);
    }
}

// ======================= one WAVE per task, zero barriers =======================
// per-task LDS slice (10048 B, x4 waves = 40192 B/block):
//  [0,2048)      surv u64[256]   -> keep int[200] after rank (surv dead in NMS)
//  [2048,5248)   box  f4[200]    (hist int[256] overlays first 1KB until rank)
//  [5248,8448)   cor  f4[200]
//  [8448,9248)   area f32[200]
//  [9248,10048)  tval f32[200]
#define TSL 10048

__global__ __launch_bounds__(NTH) void wave_select_k(const float* __restrict__ loc,
                                                     const int* __restrict__ cnt,
                                                     const uint2* __restrict__ cand,
                                                     int* __restrict__ flags,
                                                     float* __restrict__ out) {
#pragma clang fp contract(off)
    const int tid  = threadIdx.x;
    const int lane = tid & 63;
    const int wv   = tid >> 6;
    const int bc   = blockIdx.x * 4 + wv;
    const int b    = bc / NCLS;
    const int c    = bc - b * NCLS;

    __shared__ __align__(16) char smem[4 * TSL];
    char* tb = smem + wv * TSL;
    unsigned long long* surv = (unsigned long long*)tb;
    int*    keep_l = (int*)tb;                     // overlays surv (post-rank)
    float4* box_s  = (float4*)(tb + 2048);
    int*    hist   = (int*)(tb + 2048);            // overlays box (pre-rank)
    float4* cor_s  = (float4*)(tb + 5248);
    float*  area_s = (float*)(tb + 8448);
    float*  tval   = (float*)(tb + 9248);

    const int M = cnt[bc];
    if (M < TOPK || M > CAP2) {                    // punt -> rescue kernel
        if (lane == 0) flags[bc] = 1;
        return;
    }
    const unsigned long long lmask_lt = (1ull << lane) - 1ull;

    // phase 1: candidates -> 12 regs/lane; zero hist
    const uint2* src = cand + (size_t)bc * CAP2;
    unsigned long long key[12];
#pragma unroll
    for (int r = 0; r < 12; ++r) {
        int i = lane + 64 * r;
        uint2 s = (i < M) ? src[i] : make_uint2(0u, 0u);
        key[r] = ((unsigned long long)s.x << 32) | (uint32_t)(~s.y);
    }
    ((int4*)hist)[lane] = make_int4(0, 0, 0, 0);
    WAVE_LGKM();

    // phase 2: 256-bucket histogram (LDS atomics, this wave only)
#pragma unroll
    for (int r = 0; r < 12; ++r) {
        if (lane + 64 * r < M) {
            uint32_t k = ((uint32_t)(key[r] >> 32) - THR_BITS) >> 10;
            atomicAdd(&hist[k > 255u ? 255u : k], 1);
        }
    }
    WAVE_LGKM();

    // phase 3: in-wave suffix scan for cutoff bucket
    int cut;
    {
        int4 h = ((const int4*)hist)[63 - lane];
        int s3 = h.w, s2 = s3 + h.z, s1 = s2 + h.y, s0 = s1 + h.x;
        int tot = s0;
#pragma unroll
        for (int d = 1; d < 64; d <<= 1) {
            int t = __shfl_up(tot, d);
            if (lane >= d) tot += t;
        }
        int before = tot - s0;
        bool hit = (before < TOPK) && (before + s0 >= TOPK);
        int mycut = 0;
        if (hit) {
            int inner = (before + s3 >= TOPK) ? 3 : (before + s2 >= TOPK) ? 2
                      : (before + s1 >= TOPK) ? 1 : 0;
            mycut = (63 - lane) * 4 + inner;
        }
        unsigned long long hm = __ballot(hit);     // exactly one hit lane
        cut = __shfl(mycut, __ffsll(hm) - 1);
    }
    const uint32_t edge = THR_BITS + ((uint32_t)cut << 10);

    // phase 4: ballot-compaction of survivors (no atomics)
    int S = 0;
#pragma unroll
    for (int r = 0; r < 12; ++r) {
        bool take = (lane + 64 * r < M) && ((uint32_t)(key[r] >> 32) >= edge);
        unsigned long long m = __ballot(take);
        if (take) {
            int pos = S + (int)__popcll(m & lmask_lt);
            if (pos < SCAP) surv[pos] = key[r];
        }
        S += (int)__popcll(m);
    }
    if (S > SCAP) {                                // statistically never
        if (lane == 0) flags[bc] = 1;
        return;
    }
    WAVE_LGKM();

    // phase 5: exact rank (u64 keys: val desc, idx asc) + fused loc gather
    unsigned long long me0 = surv[lane], me1 = surv[lane + 64], me2 = surv[lane + 128];
    unsigned long long me3 = (lane + 192 < S) ? surv[lane + 192] : ~0ull;
    int r0 = 0, r1 = 0, r2 = 0, r3 = 0;
#pragma unroll 4
    for (int j = 0; j < S; ++j) {
        unsigned long long kj = surv[j];
        r0 += kj > me0; r1 += kj > me1; r2 += kj > me2; r3 += kj > me3;
    }
    const float4* loc4 = (const float4*)(loc + ((size_t)b * N_) * 4);
    auto place = [&](unsigned long long me, int rk, bool valid) {
        if (valid && rk < TOPK) {
            int idx = (int)(~(uint32_t)me);
            float4 bx = loc4[idx];
            float hw = bx.z * 0.5f;
            float hh = bx.w * 0.5f;
            float4 cr = make_float4(bx.x - hw, bx.y - hh, bx.x + hw, bx.y + hh);
            box_s[rk] = bx;
            cor_s[rk] = cr;
            area_s[rk] = (cr.z - cr.x) * (cr.w - cr.y);
            tval[rk]  = __uint_as_float((uint32_t)(me >> 32));
        }
    };
    place(me0, r0, true);
    place(me1, r1, true);
    place(me2, r2, true);
    place(me3, r3, lane + 192 < S);
    WAVE_LGKM();

    // phase 6: fused NMS — sequential greedy over rows, cols in 4 ballot words.
    // lane's columns: d0=lane, d1=64+lane, d2=128+lane, d3=192+lane (lane<8)
    float4 d0 = cor_s[lane], d1 = cor_s[64 + lane], d2 = cor_s[128 + lane];
    float4 d3 = (lane < 8) ? cor_s[192 + lane] : d0;
    float ab0 = area_s[lane], ab1 = area_s[64 + lane], ab2 = area_s[128 + lane];
    float ab3 = (lane < 8) ? area_s[192 + lane] : 0.0f;
    unsigned long long k0 = ~0ull, k1 = ~0ull, k2 = ~0ull, k3 = (1ull << 8) - 1ull;

    auto iou_gt = [&](float4 a, float aa, float4 d, float ab) -> bool {
        float ltx = fmaxf(a.x, d.x), lty = fmaxf(a.y, d.y);
        float rbx = fminf(a.z, d.z), rby = fminf(a.w, d.w);
        float w = fmaxf(rbx - ltx, 0.0f);
        float h = fmaxf(rby - lty, 0.0f);
        float inter = w * h;
        float U = (aa + ab) - inter;
        return ((double)inter > M_IOU * (double)U);
    };

    float4 crn = cor_s[0];
    float  arn = area_s[0];
#define NMS_ROWS(W, KW, APPLY)                                            \
    for (int ii = 0; ii < 64; ++ii) {                                     \
        const int i = W * 64 + ii;                                        \
        if (i >= TOPK) break;                                             \
        float4 a = crn; float aa = arn;                                   \
        if (i + 1 < TOPK) { crn = cor_s[i + 1]; arn = area_s[i + 1]; }    \
        if ((KW >> ii) & 1ull) {                                          \
            unsigned long long gt = ~((2ull << ii) - 1ull);               \
            APPLY                                                         \
        }                                                                 \
    }
    NMS_ROWS(0, k0, {
        unsigned long long m0 = __ballot(iou_gt(a, aa, d0, ab0));
        unsigned long long m1 = __ballot(iou_gt(a, aa, d1, ab1));
        unsigned long long m2 = __ballot(iou_gt(a, aa, d2, ab2));
        unsigned long long m3 = __ballot(iou_gt(a, aa, d3, ab3));
        k0 &= ~(m0 & gt); k1 &= ~m1; k2 &= ~m2; k3 &= ~m3;
    })
    NMS_ROWS(1, k1, {
        unsigned long long m1 = __ballot(iou_gt(a, aa, d1, ab1));
        unsigned long long m2 = __ballot(iou_gt(a, aa, d2, ab2));
        unsigned long long m3 = __ballot(iou_gt(a, aa, d3, ab3));
        k1 &= ~(m1 & gt); k2 &= ~m2; k3 &= ~m3;
    })
    NMS_ROWS(2, k2, {
        unsigned long long m2 = __ballot(iou_gt(a, aa, d2, ab2));
        unsigned long long m3 = __ballot(iou_gt(a, aa, d3, ab3));
        k2 &= ~(m2 & gt); k3 &= ~m3;
    })
    NMS_ROWS(3, k3, {
        unsigned long long m3 = __ballot(iou_gt(a, aa, d3, ab3));
        k3 &= ~(m3 & gt);
    })
#undef NMS_ROWS

    // phase 7: keep bits -> LDS (surv arena dead), then coalesced output
    keep_l[lane]       = (int)((k0 >> lane) & 1ull);
    keep_l[64 + lane]  = (int)((k1 >> lane) & 1ull);
    keep_l[128 + lane] = (int)((k2 >> lane) & 1ull);
    if (lane < 8) keep_l[192 + lane] = (int)((k3 >> lane) & 1ull);
    WAVE_LGKM();

    const float cls_f = (float)c;
    float* obase = out + (size_t)bc * (TOPK * 6);
#pragma unroll 1
    for (int t = 0; t < 19; ++t) {
        int k = lane + 64 * t;
        if (k < TOPK * 6) {
            int rk = (k * 10923) >> 16;            // k/6
            int f  = k - rk * 6;
            float val;
            if (f == 0)      val = cls_f;
            else if (f == 1) val = tval[rk];
            else             val = ((const float*)box_s)[rk * 4 + (f - 2)];
            obase[k] = keep_l[rk] ? val : -1.0f;
        }
    }
    float* kbase = out + (size_t)NBC * (TOPK * 6) + (size_t)bc * TOPK;
#pragma unroll
    for (int t = 0; t < 4; ++t) {
        int rk = lane + 64 * t;
        if (rk < TOPK) kbase[rk] = keep_l[rk] ? 1.0f : 0.0f;
    }
}

// ======================= rescue: R6 block kernel, flag-gated =======================
#define SUPS      5
#define SM_A      0
#define SM_B      8000
#define SM_BOX    8000
#define SM_COR    11200
#define SM_TVAL   14400
#define SM_TIDX   15200
#define SM_CTRL   16000
#define SM_KEEPW  16016
#define SM_AREA   16048
#define SM_TOTAL  16848

__global__ __launch_bounds__(NTH) void rescue_k(const float* __restrict__ conf,
                                                const float* __restrict__ loc,
                                                const int* __restrict__ cnt,
                                                const uint2* __restrict__ cand,
                                                const int* __restrict__ flags,
                                                float* __restrict__ out,
                                                int use_ws) {
#pragma clang fp contract(off)
    const int bc = blockIdx.x;
    if (flags && flags[bc] == 0) return;           // handled by wave_select_k
    const int b   = bc / NCLS;
    const int c   = bc - b * NCLS;
    const int tid = threadIdx.x;
    const int lane = tid & 63;
    const int wv   = tid >> 6;

    __shared__ __align__(16) char smem[SM_TOTAL];
    unsigned long long* surv = (unsigned long long*)(smem + SM_A);
    unsigned long long* sup  = (unsigned long long*)(smem + SM_A);
    float*  ostage = (float*)(smem + SM_A);
    int*    hist   = (int*)(smem + SM_B);
    float4* box_s  = (float4*)(smem + SM_BOX);
    float4* cor_s  = (float4*)(smem + SM_COR);
    float*  top_val = (float*)(smem + SM_TVAL);
    int*    top_idx = (int*)(smem + SM_TIDX);
    int*    ctrl   = (int*)(smem + SM_CTRL);
    unsigned long long* keepw = (unsigned long long*)(smem + SM_KEEPW);
    float*  area_s = (float*)(smem + SM_AREA);

    int M = use_ws ? cnt[bc] : 0;
    const bool fast = use_ws && (M >= TOPK) && (M <= CAP2);
    int S = 0;

    if (fast) {
        const uint2* src = cand + (size_t)bc * CAP2;
        uint2 my0 = make_uint2(0u, 0u), my1 = make_uint2(0u, 0u), my2 = make_uint2(0u, 0u);
        if (tid           < M) my0 = src[tid];
        if (tid +     NTH < M) my1 = src[tid + NTH];
        if (tid + 2 * NTH < M) my2 = src[tid + 2 * NTH];
        hist[tid] = 0;
        if (tid == 0) ctrl[2] = 0;
        __syncthreads();
        if (tid           < M) { uint32_t k = (my0.x - THR_BITS) >> 10; atomicAdd(&hist[k > 255u ? 255u : k], 1); }
        if (tid +     NTH < M) { uint32_t k = (my1.x - THR_BITS) >> 10; atomicAdd(&hist[k > 255u ? 255u : k], 1); }
        if (tid + 2 * NTH < M) { uint32_t k = (my2.x - THR_BITS) >> 10; atomicAdd(&hist[k > 255u ? 255u : k], 1); }
        __syncthreads();
        if (tid < 64) {
            int4 h = ((const int4*)hist)[63 - tid];
            int s3 = h.w, s2 = s3 + h.z, s1 = s2 + h.y, s0 = s1 + h.x;
            int tot = s0;
#pragma unroll
            for (int d = 1; d < 64; d <<= 1) {
                int t = __shfl_up(tot, d);
                if (tid >= d) tot += t;
            }
            int before = tot - s0;
            if (before < TOPK && before + s0 >= TOPK) {
                int inner = (before + s3 >= TOPK) ? 3 : (before + s2 >= TOPK) ? 2
                          : (before + s1 >= TOPK) ? 1 : 0;
                ctrl[1] = (63 - tid) * 4 + inner;
            }
        }
        __syncthreads();
        if (tid < TOPK) {
            top_idx[tid] = -1;
            area_s[tid] = 0.0f;
            box_s[tid] = make_float4(-1.f, -1.f, -1.f, -1.f);
            cor_s[tid] = make_float4(0.f, 0.f, 0.f, 0.f);
        }
        const uint32_t edge = THR_BITS + ((uint32_t)ctrl[1] << 10);
#define COMPACT(MY)                                                          \
        {                                                                    \
            bool take = (MY.x >= edge);                                      \
            unsigned long long mask = __ballot(take);                        \
            int base = 0;                                                    \
            if (lane == 0 && mask) base = atomicAdd(&ctrl[2], (int)__popcll(mask)); \
            base = __shfl(base, 0);                                          \
            if (take) {                                                      \
                int pos = base + (int)__popcll(mask & ((1ull << lane) - 1ull)); \
                if (pos < CAP2)                                              \
                    surv[pos] = ((unsigned long long)MY.x << 32) | (uint32_t)(~MY.y); \
            }                                                                \
        }
        COMPACT(my0) COMPACT(my1) COMPACT(my2)
#undef COMPACT
        __syncthreads();
        S = min(ctrl[2], CAP2);
    } else {
        for (int k = tid; k < HBUCK; k += NTH) hist[k] = 0;
        if (tid == 0) ctrl[2] = 0;
        __syncthreads();
        const float* col = conf + ((size_t)b * N_) * C_ + c;
        for (int n = tid; n < N_; n += NTH) {
            float v = col[(size_t)n * C_];
            if (v >= 0.5f) {
                int bkt = (int)(__float_as_uint(v) >> 13) - HBASE;
                atomicAdd(&hist[min(bkt, HBUCK - 1)], 1);
            }
        }
        __syncthreads();
        if (tid == 0) {
            int acc = 0, cut = -1;
            for (int k = HBUCK - 1; k >= 0; --k) {
                acc += hist[k];
                if (acc >= TOPK) { cut = k; break; }
            }
            ctrl[1] = cut;
        }
        __syncthreads();
        const int   cutv = ctrl[1];
        const float vcut = (cutv >= 0) ? __uint_as_float((uint32_t)(HBASE + cutv) << 13)
                                       : CONF_T;
        for (int n = tid; n < N_; n += NTH) {
            float v = col[(size_t)n * C_];
            bool take = (cutv >= 0) ? (v >= vcut) : (v > CONF_T);
            if (take) {
                int p = atomicAdd(&ctrl[2], 1);
                if (p < CAP2)
                    surv[p] = ((unsigned long long)__float_as_uint(v) << 32)
                            | (uint32_t)(~(uint32_t)n);
            }
        }
        __syncthreads();
        if (tid < TOPK) {
            top_idx[tid] = -1;
            area_s[tid] = 0.0f;
            box_s[tid] = make_float4(-1.f, -1.f, -1.f, -1.f);
            cor_s[tid] = make_float4(0.f, 0.f, 0.f, 0.f);
        }
        S = min(ctrl[2], CAP2);
        __syncthreads();
    }

    for (int i = tid; i < S; i += NTH) {
        unsigned long long me = surv[i];
        int rank = 0;
#pragma unroll 4
        for (int j = 0; j < S; ++j)
            rank += (surv[j] > me);
        if (rank < TOPK) {
            int idx = (int)(~(uint32_t)me);
            top_val[rank] = __uint_as_float((uint32_t)(me >> 32));
            top_idx[rank] = idx;
            float4 bx = *(const float4*)(loc + ((size_t)b * N_ + (size_t)idx) * 4);
            float hw = bx.z * 0.5f;
            float hh = bx.w * 0.5f;
            float4 cr = make_float4(bx.x - hw, bx.y - hh, bx.x + hw, bx.y + hh);
            box_s[rank] = bx;
            cor_s[rank] = cr;
            area_s[rank] = (cr.z - cr.x) * (cr.w - cr.y);
        }
    }
    __syncthreads();

    {
        bool v = (tid < TOPK) && (top_idx[tid] >= 0);
        unsigned long long m = __ballot(v);
        if (lane == 0) keepw[wv] = m;
    }

    {
        const int j = tid;
        float4 d = make_float4(0.f, 0.f, 0.f, 0.f);
        float  areaB = 0.0f;
        const bool jv = (j < TOPK);
        if (jv) { d = cor_s[j]; areaB = area_s[j]; }
#pragma unroll 2
        for (int i = 0; i < TOPK; ++i) {
            float4 a = cor_s[i];
            bool s = false;
            if (jv && j > i) {
                float ltx = fmaxf(a.x, d.x), lty = fmaxf(a.y, d.y);
                float rbx = fminf(a.z, d.z), rby = fminf(a.w, d.w);
                float w  = fmaxf(rbx - ltx, 0.0f);
                float h  = fmaxf(rby - lty, 0.0f);
                float inter = w * h;
                float U = (area_s[i] + areaB) - inter;
                s = ((double)inter > M_IOU * (double)U);
            }
            unsigned long long m = __ballot(s);
            if (lane == 0) sup[i * SUPS + wv] = m;
        }
    }
    __syncthreads();

    if (tid < 64) {
        unsigned long long r0[4], r1[4], r2[4], r3[4];
#pragma unroll
        for (int w = 0; w < 4; ++w) {
            r0[w] = sup[(0 * 64 + tid) * SUPS + w];
            r1[w] = sup[(1 * 64 + tid) * SUPS + w];
            r2[w] = sup[(2 * 64 + tid) * SUPS + w];
            r3[w] = (192 + tid < TOPK) ? sup[(192 + tid) * SUPS + w] : 0ull;
        }
        unsigned long long k0 = keepw[0], k1 = keepw[1], k2 = keepw[2], k3 = keepw[3];
#define GREEDY_BLK(KW, RR)                                            \
        for (int ii = 0; ii < 64; ++ii) {                             \
            if ((KW >> ii) & 1ull) {                                  \
                k0 &= ~__shfl(RR[0], ii);                             \
                k1 &= ~__shfl(RR[1], ii);                             \
                k2 &= ~__shfl(RR[2], ii);                             \
                k3 &= ~__shfl(RR[3], ii);                             \
            }                                                         \
        }
        GREEDY_BLK(k0, r0)
        GREEDY_BLK(k1, r1)
        GREEDY_BLK(k2, r2)
        GREEDY_BLK(k3, r3)
#undef GREEDY_BLK
        if (tid == 0) { keepw[0] = k0; keepw[1] = k1; keepw[2] = k2; keepw[3] = k3; }
    }
    __syncthreads();

    if (tid < TOPK) {
        const bool kp = (keepw[tid >> 6] >> (tid & 63)) & 1ull;
        float4 bx = box_s[tid];
        float* o = ostage + tid * 6;
        if (kp) {
            o[0] = (float)c;   o[1] = top_val[tid];
            o[2] = bx.x; o[3] = bx.y; o[4] = bx.z; o[5] = bx.w;
        } else {
            o[0] = -1.f; o[1] = -1.f; o[2] = -1.f;
            o[3] = -1.f; o[4] = -1.f; o[5] = -1.f;
        }
        out[(size_t)NBC * TOPK * 6 + (size_t)bc * TOPK + tid] = kp ? 1.0f : 0.0f;
    }
    __syncthreads();
    {
        float4* dst = (float4*)(out + (size_t)bc * TOPK * 6);
        const float4* src4 = (const float4*)ostage;
        for (int k = tid; k < TOPK * 6 / 4; k += NTH) dst[k] = src4[k];
    }
}

extern "C" void kernel_launch(void* const* d_in, const int* in_sizes, int n_in,
                              void* d_out, int out_size, void* d_ws, size_t ws_size,
                              hipStream_t stream) {
    (void)in_sizes; (void)n_in; (void)out_size;
    const float* loc  = (const float*)d_in[0];
    const float* conf = (const float*)d_in[1];
    float* out = (float*)d_out;

    const bool use_ws = (d_ws != nullptr) && (ws_size >= WS_NEED);
    int*   cnt   = (int*)((char*)d_ws + OFF_CNT);
    int*   flags = (int*)((char*)d_ws + OFF_FLAGS);
    uint2* cand  = (uint2*)((char*)d_ws + OFF_CAND);

    if (use_ws) {
        hipLaunchKernelGGL(zero_hdr, dim3(32), dim3(NTH), 0, stream, cnt);
        hipLaunchKernelGGL(filter_k, dim3(B_ * NCHUNK), dim3(NTH), 0, stream,
                           conf, cnt, cand);
        hipLaunchKernelGGL(wave_select_k, dim3(NBC / 4), dim3(NTH), 0, stream,
                           loc, cnt, cand, flags, out);
        hipLaunchKernelGGL(rescue_k, dim3(NBC), dim3(NTH), 0, stream,
                           conf, loc, cnt, cand, flags, out, 1);
    } else {
        hipLaunchKernelGGL(rescue_k, dim3(NBC), dim3(NTH), 0, stream,
                           conf, loc, (const int*)nullptr, (const uint2*)nullptr,
                           (const int*)nullptr, out, 0);
    }
}